// Round 11
// baseline (282.494 us; speedup 1.0000x reference)
//
#include <hip/hip_runtime.h>
#include <hip/hip_bf16.h>

#define B_ 4
#define S_ 2048
#define D_ 768
#define H_ 12
#define HD 64

typedef __attribute__((ext_vector_type(8))) short short8;
typedef __attribute__((ext_vector_type(4))) float f32x4;

__device__ __forceinline__ float fmapf(float x) { return x > 0.f ? x + 1.f : __expf(x); }

// fp32 -> bf16 round-to-nearest-even (finite inputs only)
__device__ __forceinline__ unsigned short f2bu(float f) {
    unsigned u = __float_as_uint(f);
    u += 0x7FFFu + ((u >> 16) & 1u);
    return (unsigned short)(u >> 16);
}
__device__ __forceinline__ float bu2f(unsigned short v) {
    return __uint_as_float((unsigned)v << 16);
}

// async global->LDS direct copy, 16B per lane. lds ptr must be wave-uniform;
// HW writes lane l to ldsbase + l*16 (m97 pattern: linear LDS dest).
__device__ __forceinline__ void gload16(const void* g, void* l) {
    __builtin_amdgcn_global_load_lds((__attribute__((address_space(1))) void*)(size_t)g,
                                     (__attribute__((address_space(3))) void*)l, 16, 0, 0);
}

union u16x8 {
    uint4 u;
    short8 s;
    unsigned short h[8];
};

// ---------------------------------------------------------------------------
// Kernel 0: fused fp32->bf16 converts for x, qkv_w, out_w + fmap(anchor_q).
// ---------------------------------------------------------------------------
__global__ __launch_bounds__(256) void convert_all(const float* __restrict__ x,
                                                   const float* __restrict__ qkvw,
                                                   const float* __restrict__ outw,
                                                   const float* __restrict__ aq,
                                                   unsigned short* __restrict__ xb,
                                                   unsigned short* __restrict__ wb,
                                                   unsigned short* __restrict__ outwb,
                                                   unsigned short* __restrict__ aqfb_g) {
    int gid = blockIdx.x * 256 + threadIdx.x;
    const float* src;
    unsigned short* dst;
    int i4;
    if (gid < 1572864) {
        src = x; dst = xb; i4 = gid;
    } else if (gid < 1572864 + 442368) {
        src = qkvw; dst = wb; i4 = gid - 1572864;
    } else if (gid < 2162688) {
        src = outw; dst = outwb; i4 = gid - (1572864 + 442368);
    } else {
        int i = gid - 2162688;  // < 9216
        aqfb_g[i] = f2bu(fmapf(aq[i]));
        return;
    }
    float4 v = *(const float4*)&src[i4 * 4];
    ushort4 o;
    o.x = f2bu(v.x); o.y = f2bu(v.y); o.z = f2bu(v.z); o.w = f2bu(v.w);
    *(ushort4*)&dst[i4 * 4] = o;
}

// ---------------------------------------------------------------------------
// Kernel 1: qkv = x @ qkv_w.T via bf16 MFMA. dbuf + XCD swizzle + counted
// vmcnt + LDS-transposed coalesced bf16 epilogue (unchanged from round 10).
// ---------------------------------------------------------------------------
__global__ __launch_bounds__(256) void qkv_gemm_mfma(const unsigned short* __restrict__ xb,
                                                     const unsigned short* __restrict__ wb,
                                                     unsigned short* __restrict__ qfb,
                                                     unsigned short* __restrict__ kfb,
                                                     unsigned short* __restrict__ vvb) {
    __shared__ __attribute__((aligned(16))) unsigned short shmem[18432];
    const int K = 768;
    int orig = blockIdx.x;
    int swz = (orig & 7) * 144 + (orig >> 3);
    int mt = swz / 18, nt = swz - mt * 18;
    int n0 = nt * 128, m0 = mt * 128;
    int tid = threadIdx.x, lane = tid & 63, wave = tid >> 6;
    int wm = (wave & 1) * 64, wn = (wave >> 1) * 64;
    int quad = lane >> 4, l15 = lane & 15;
    f32x4 acc[4][4];
#pragma unroll
    for (int i = 0; i < 4; i++)
#pragma unroll
        for (int j = 0; j < 4; j++) acc[i][j] = 0.f;

    const unsigned short* ga0 = xb + (size_t)(m0 + (tid >> 2)) * K + (tid & 3) * 8;
    const unsigned short* ga1 = xb + (size_t)(m0 + 64 + (tid >> 2)) * K + (tid & 3) * 8;
    const unsigned short* gb0 = wb + (size_t)(n0 + (tid >> 2)) * K + (tid & 3) * 8;
    const unsigned short* gb1 = wb + (size_t)(n0 + 64 + (tid >> 2)) * K + (tid & 3) * 8;

    auto stage = [&](int bufi, int kk) {
        gload16(ga0 + kk, shmem + bufi * 4096 + wave * 512);
        gload16(ga1 + kk, shmem + bufi * 4096 + 2048 + wave * 512);
        gload16(gb0 + kk, shmem + 8192 + bufi * 4096 + wave * 512);
        gload16(gb1 + kk, shmem + 8192 + bufi * 4096 + 2048 + wave * 512);
    };
    auto compute = [&](int bufi) {
        short8 af[4], bfr[4];
#pragma unroll
        for (int i = 0; i < 4; i++)
            af[i] = *(short8*)&shmem[bufi * 4096 + (wm + i * 16 + l15) * 32 + quad * 8];
#pragma unroll
        for (int j = 0; j < 4; j++)
            bfr[j] = *(short8*)&shmem[8192 + bufi * 4096 + (wn + j * 16 + l15) * 32 + quad * 8];
#pragma unroll
        for (int i = 0; i < 4; i++)
#pragma unroll
            for (int j = 0; j < 4; j++)
                acc[i][j] = __builtin_amdgcn_mfma_f32_16x16x32_bf16(af[i], bfr[j], acc[i][j], 0, 0, 0);
    };

    stage(0, 0);
    int buf = 0;
    for (int t = 0; t < 23; t++) {
        stage(buf ^ 1, (t + 1) * 32);
        asm volatile("s_waitcnt vmcnt(4)" ::: "memory");
        __builtin_amdgcn_s_barrier();
        __builtin_amdgcn_sched_barrier(0);
        compute(buf);
        asm volatile("" ::: "memory");
        __builtin_amdgcn_s_barrier();
        buf ^= 1;
    }
    asm volatile("s_waitcnt vmcnt(0)" ::: "memory");
    __builtin_amdgcn_s_barrier();
    __builtin_amdgcn_sched_barrier(0);
    compute(buf);

    // ---- epilogue: LDS-transposed coalesced store ----
    __syncthreads();
    {
        int colbase = n0 + wn;            // 64-aligned -> t3, h wave-uniform
        int t3 = colbase / 768;
        int r = colbase - t3 * 768;
        int h = r >> 6;
        int mstart = m0 + wm;
        int bb = mstart >> 11, sstart = mstart & 2047;
        unsigned short* ldsw = shmem + wave * 4608;  // [64 tok][72]
#pragma unroll
        for (int j = 0; j < 4; j++)
#pragma unroll
            for (int i = 0; i < 4; i++)
#pragma unroll
                for (int rr = 0; rr < 4; rr++) {
                    float val = acc[i][j][rr];
                    unsigned short o = (t3 == 2) ? f2bu(val) : f2bu(fmapf(val));
                    ldsw[(i * 16 + quad * 4 + rr) * 72 + j * 16 + l15] = o;
                }
        unsigned short* gb = (t3 == 0 ? qfb : (t3 == 1 ? kfb : vvb)) +
                             (((size_t)(bb * H_ + h) * S_) + sstart) * (size_t)HD;
#pragma unroll
        for (int c = 0; c < 8; c++) {
            int tok = c * 8 + (lane >> 3);
            uint4 vd = *(uint4*)&ldsw[tok * 72 + (lane & 7) * 8];
            *(uint4*)&gb[(size_t)tok * 64 + (lane & 7) * 8] = vd;
        }
    }
}

// ---------------------------------------------------------------------------
// Kernel 2a: partial kv states — pure streaming. Grid doubled: 48 bh * 32
// chunks (64 tokens each) -> 1536 blocks = 6 blocks/CU (occupancy ~75%) to
// hide L2 latency with TLP. Same terms, chunk-level re-association only.
// ---------------------------------------------------------------------------
__global__ __launch_bounds__(256) void band_partial(const unsigned short* __restrict__ kfb,
                                                    const unsigned short* __restrict__ vvb,
                                                    float* __restrict__ pkv,
                                                    float* __restrict__ pks) {
    int bh = blockIdx.x >> 5, chunk = blockIdx.x & 31;
    int sbase = chunk * 64;
    const unsigned short* kfp = kfb + (size_t)bh * S_ * HD + (size_t)sbase * HD;
    const unsigned short* vp = vvb + (size_t)bh * S_ * HD + (size_t)sbase * HD;
    int tid = threadIdx.x;
    int d = tid & 63, eg = tid >> 6, e0 = eg * 16;
    float accg[16], accs[16];
#pragma unroll
    for (int i = 0; i < 16; i++) { accg[i] = 0.f; accs[i] = 0.f; }
    float ksg = 0.f, kss = 0.f;
#pragma unroll 4
    for (int s = 0; s < 64; s++) {
        float kd = bu2f(kfp[(size_t)s * HD + d]);
        bool str = ((sbase + s) % 3) == 0;
        ksg += kd;
        u16x8 va, vb2;
        va.u = *(const uint4*)&vp[(size_t)s * HD + e0];
        vb2.u = *(const uint4*)&vp[(size_t)s * HD + e0 + 8];
        float vf[16];
#pragma unroll
        for (int i = 0; i < 8; i++) vf[i] = bu2f(va.h[i]);
#pragma unroll
        for (int i = 0; i < 8; i++) vf[8 + i] = bu2f(vb2.h[i]);
#pragma unroll
        for (int i = 0; i < 16; i++) accg[i] += kd * vf[i];
        if (str) {
            kss += kd;
#pragma unroll
            for (int i = 0; i < 16; i++) accs[i] += kd * vf[i];
        }
    }
    float* pg = pkv + (size_t)blockIdx.x * 2 * 4096;
#pragma unroll
    for (int i = 0; i < 16; i++) pg[d * 64 + e0 + i] = accg[i];
#pragma unroll
    for (int i = 0; i < 16; i++) pg[4096 + d * 64 + e0 + i] = accs[i];
    if (eg == 0) {
        pks[blockIdx.x * 128 + d] = ksg;
        pks[blockIdx.x * 128 + 64 + d] = kss;
    }
}

// ---------------------------------------------------------------------------
// Kernel 2b: reduce partials (now 32/bh) + anchor outputs. Grid = 48*4.
// ---------------------------------------------------------------------------
__global__ __launch_bounds__(256) void band_reduce(const float* __restrict__ pkv,
                                                   const float* __restrict__ pks,
                                                   const float* __restrict__ aq,
                                                   unsigned short* __restrict__ kvsTb,
                                                   unsigned short* __restrict__ ksumsb,
                                                   unsigned short* __restrict__ aoutTb) {
    int bh = blockIdx.x >> 2, eb = blockIdx.x & 3, e0 = eb * 16;
    int h = bh % H_;
    __shared__ float kvgL[64][17];
    __shared__ float ksgL[64];
    __shared__ float anorm[12];
    int tid = threadIdx.x;
    for (int idx = tid; idx < 1024; idx += 256) {
        int d = idx >> 4, j = idx & 15;
        float sg = 0.f, ss = 0.f;
        const float* p = pkv + (size_t)(bh * 32) * 2 * 4096 + d * 64 + e0 + j;
#pragma unroll 4
        for (int c = 0; c < 32; c++) {
            sg += p[0];
            ss += p[4096];
            p += 2 * 4096;
        }
        kvgL[d][j] = sg;
        kvsTb[(size_t)bh * 4096 + (e0 + j) * 64 + d] = f2bu(ss);
    }
    if (tid < 64) {
        float sg = 0.f, ss = 0.f;
#pragma unroll 4
        for (int c = 0; c < 32; c++) {
            sg += pks[(bh * 32 + c) * 128 + tid];
            ss += pks[(bh * 32 + c) * 128 + 64 + tid];
        }
        ksgL[tid] = sg;
        if (eb == 0) ksumsb[bh * 64 + tid] = f2bu(ss);
    }
    __syncthreads();
    if (tid < 12) {
        float nrm = 0.f;
        for (int dd = 0; dd < 64; dd++)
            nrm += fmapf(aq[h * 768 + tid * 64 + dd]) * ksgL[dd];
        anorm[tid] = fmaxf(nrm, 1e-6f);
    }
    __syncthreads();
    if (tid < 192) {
        int a = tid >> 4, j = tid & 15;
        float acc = 0.f;
        for (int dd = 0; dd < 64; dd++)
            acc += fmapf(aq[h * 768 + a * 64 + dd]) * kvgL[dd][j];
        aoutTb[(size_t)bh * 768 + (e0 + j) * 12 + a] = f2bu(acc / anorm[a]);
    }
}

// ---------------------------------------------------------------------------
// Kernel 3: combine — register-direct MFMA fragments (unchanged).
// ---------------------------------------------------------------------------
__global__ __launch_bounds__(256) void combine(const unsigned short* __restrict__ qfb,
                                               const unsigned short* __restrict__ kfb,
                                               const unsigned short* __restrict__ vvb,
                                               const unsigned short* __restrict__ aqfb_g,
                                               const unsigned short* __restrict__ kvsTb,
                                               const unsigned short* __restrict__ ksumsb,
                                               const unsigned short* __restrict__ aoutTb,
                                               const float* __restrict__ wlp,
                                               const float* __restrict__ wsp,
                                               const float* __restrict__ wgp,
                                               unsigned short* __restrict__ attnb) {
    __shared__ __attribute__((aligned(16))) unsigned short aqfb[16][72];   // anchors + ksum
    __shared__ __attribute__((aligned(16))) unsigned short vtbT[64][104];  // [e][band k], k<96
    __shared__ __attribute__((aligned(16))) unsigned short plb[64][104];   // masked P
    __shared__ __attribute__((aligned(16))) unsigned short qkgb[64][40];   // [token][anchor k]
    __shared__ float nrm[4][3][16];
    int bh = blockIdx.x >> 5, stile = blockIdx.x & 31;
    int b = bh / H_, h = bh % H_;
    int s0 = stile * 64;
    int tid = threadIdx.x, lane = tid & 63, wave = tid >> 6;
    int quad = lane >> 4, l15 = lane & 15;
    const unsigned short* qfp = qfb + (size_t)bh * S_ * HD;
    const unsigned short* kfp = kfb + (size_t)bh * S_ * HD;
    const unsigned short* vp = vvb + (size_t)bh * S_ * HD;
    float a0 = wlp[0], a1 = wsp[0], a2 = wgp[0];
    float mx = fmaxf(a0, fmaxf(a1, a2));
    float ew0 = __expf(a0 - mx), ew1 = __expf(a1 - mx), ew2 = __expf(a2 - mx);
    float inv = 1.f / (ew0 + ew1 + ew2);
    float wl = ew0 * inv, wsb = ew1 * inv, wg = ew2 * inv;
    // ---- stage: vtbT (bf16 copy transpose), aqfb, K-pads ----
    for (int i = tid; i < 96 * 64; i += 256) {
        int k = i >> 6, e = i & 63;
        int gs = s0 + k - 6;
        unsigned short v_ = (k < 75 && gs >= 0 && gs < S_) ? vp[(size_t)gs * HD + e]
                                                           : (unsigned short)0;
        vtbT[e][k] = v_;
    }
    if (tid < 192) {
        int a = tid >> 4, c = (tid & 15) * 4;
        *(ushort4*)&aqfb[a][c] = *(const ushort4*)&aqfb_g[h * 768 + a * 64 + c];
    }
    if (tid < 64) aqfb[12][tid] = ksumsb[bh * 64 + tid];
    if (tid < 192) aqfb[13 + (tid >> 6)][tid & 63] = 0;
    for (int i = tid; i < 1024; i += 256) {
        plb[i >> 4][80 + (i & 15)] = 0;   // K-pad cols 80..95
        qkgb[i >> 4][16 + (i & 15)] = 0;  // K-pad cols 16..31
    }
    __syncthreads();
    // ---- q A-fragments: per-thread rows, loaded once, reused everywhere ----
    u16x8 qa0, qa1;
    {
        const unsigned short* qr = qfp + (size_t)(s0 + wave * 16 + l15) * HD + quad * 8;
        qa0.u = *(const uint4*)qr;
        qa1.u = *(const uint4*)(qr + 32);
    }
    // ---- phase A: wave w computes P rows w*16..w*16+15 (wave-private) ----
#pragma unroll
    for (int tj = 0; tj < 5; tj++) {
        int row = tj * 16 + l15;
        int gs = s0 + row - 6;
        bool valid = (row < 75) && (gs >= 0) && (gs < S_);
        int gsc = gs < 0 ? 0 : (gs > S_ - 1 ? S_ - 1 : gs);
        const unsigned short* kr = kfp + (size_t)gsc * HD + quad * 8;
        u16x8 b0, b1, ones;
        ones.u = make_uint4(0x3F803F80u, 0x3F803F80u, 0x3F803F80u, 0x3F803F80u);
        b0.u = *(const uint4*)kr;
        b1.u = *(const uint4*)(kr + 32);
        if (!valid) { b0 = ones; b1 = ones; }
        f32x4 c = {0.f, 0.f, 0.f, 0.f};
        c = __builtin_amdgcn_mfma_f32_16x16x32_bf16(qa0.s, b0.s, c, 0, 0, 0);
        c = __builtin_amdgcn_mfma_f32_16x16x32_bf16(qa1.s, b1.s, c, 0, 0, 0);
        int col = tj * 16 + l15;
#pragma unroll
        for (int rr = 0; rr < 4; rr++) {
            int tok = wave * 16 + quad * 4 + rr;
            int which = col - tok;
            plb[tok][col] = (which >= 0 && which < 12) ? f2bu(c[rr]) : (unsigned short)0;
        }
    }
    {
        f32x4 c = {0.f, 0.f, 0.f, 0.f};
        short8 bfr0 = *(short8*)&aqfb[l15][quad * 8];
        short8 bfr1 = *(short8*)&aqfb[l15][32 + quad * 8];
        c = __builtin_amdgcn_mfma_f32_16x16x32_bf16(qa0.s, bfr0, c, 0, 0, 0);
        c = __builtin_amdgcn_mfma_f32_16x16x32_bf16(qa1.s, bfr1, c, 0, 0, 0);
#pragma unroll
        for (int rr = 0; rr < 4; rr++) qkgb[wave * 16 + quad * 4 + rr][l15] = f2bu(c[rr]);
    }
    // ---- per-wave norms -> reciprocal combine weights (lanes 0-15) ----
    if (lane < 16) {
        int t = wave * 16 + lane;
        float sl = 0.f;
#pragma unroll
        for (int j = 0; j < 12; j++) sl += bu2f(plb[t][t + j]);
        float sg = 0.f;
#pragma unroll
        for (int a = 0; a < 12; a++) sg += bu2f(qkgb[t][a]);
        nrm[wave][0][lane] = wl / fmaxf(sl, 1e-6f);
        nrm[wave][1][lane] = wg / fmaxf(sg, 1e-6f);
        nrm[wave][2][lane] = wsb / fmaxf(bu2f(qkgb[t][12]), 1e-6f);
    }
    // ---- phase B: fused MFMA; B-frags for stride/global bands direct ----
#pragma unroll
    for (int j2 = 0; j2 < 4; j2++) {
        int e = j2 * 16 + l15;
        f32x4 cL = {0.f, 0.f, 0.f, 0.f};
        f32x4 cG = {0.f, 0.f, 0.f, 0.f};
        f32x4 cS = {0.f, 0.f, 0.f, 0.f};
#pragma unroll
        for (int kk = 0; kk < 3; kk++) {
            short8 afr = *(short8*)&plb[wave * 16 + l15][kk * 32 + quad * 8];
            short8 bfr = *(short8*)&vtbT[e][kk * 32 + quad * 8];
            cL = __builtin_amdgcn_mfma_f32_16x16x32_bf16(afr, bfr, cL, 0, 0, 0);
        }
        {
            short8 afr = *(short8*)&qkgb[wave * 16 + l15][quad * 8];
            u16x8 bo;
            bo.u = make_uint4(0u, 0u, 0u, 0u);
            const unsigned* ap = (const unsigned*)(aoutTb + (size_t)bh * 768 + e * 12);
            if (quad == 0) {
                bo.u.x = ap[0]; bo.u.y = ap[1]; bo.u.z = ap[2]; bo.u.w = ap[3];
            } else if (quad == 1) {
                bo.u.x = ap[4]; bo.u.y = ap[5];
            }
            cG = __builtin_amdgcn_mfma_f32_16x16x32_bf16(afr, bo.s, cG, 0, 0, 0);
        }
        {
            const unsigned short* kvp = kvsTb + (size_t)bh * 4096 + e * 64 + quad * 8;
            u16x8 bk0, bk1;
            bk0.u = *(const uint4*)kvp;
            bk1.u = *(const uint4*)(kvp + 32);
            cS = __builtin_amdgcn_mfma_f32_16x16x32_bf16(qa0.s, bk0.s, cS, 0, 0, 0);
            cS = __builtin_amdgcn_mfma_f32_16x16x32_bf16(qa1.s, bk1.s, cS, 0, 0, 0);
        }
#pragma unroll
        for (int rr = 0; rr < 4; rr++) {
            int tq = quad * 4 + rr;
            int tok = wave * 16 + tq;
            float res = cL[rr] * nrm[wave][0][tq] + cS[rr] * nrm[wave][2][tq] +
                        cG[rr] * nrm[wave][1][tq];
            attnb[((size_t)(b * S_ + s0 + tok)) * 768 + h * 64 + e] = f2bu(res);
        }
    }
}

// ---------------------------------------------------------------------------
// Kernel 4: out = attn(bf16) @ out_w.T, counted-vmcnt dbuf + XCD swizzle.
// ---------------------------------------------------------------------------
__global__ __launch_bounds__(256) void out_gemm_mfma(const unsigned short* __restrict__ attnb,
                                                     const unsigned short* __restrict__ wb,
                                                     float* __restrict__ out) {
    __shared__ __attribute__((aligned(16))) unsigned short As[2][128 * 32];
    __shared__ __attribute__((aligned(16))) unsigned short Bs[2][128 * 32];
    const int K = 768;
    int orig = blockIdx.x;
    int swz = (orig & 7) * 48 + (orig >> 3);
    int mt = swz / 6, nt = swz - mt * 6;
    int n0 = nt * 128, m0 = mt * 128;
    int tid = threadIdx.x, lane = tid & 63, wave = tid >> 6;
    int wm = (wave & 1) * 64, wn = (wave >> 1) * 64;
    int quad = lane >> 4, l15 = lane & 15;
    f32x4 acc[4][4];
#pragma unroll
    for (int i = 0; i < 4; i++)
#pragma unroll
        for (int j = 0; j < 4; j++) acc[i][j] = 0.f;

    const unsigned short* ga0 = attnb + (size_t)(m0 + (tid >> 2)) * K + (tid & 3) * 8;
    const unsigned short* ga1 = attnb + (size_t)(m0 + 64 + (tid >> 2)) * K + (tid & 3) * 8;
    const unsigned short* gb0 = wb + (size_t)(n0 + (tid >> 2)) * K + (tid & 3) * 8;
    const unsigned short* gb1 = wb + (size_t)(n0 + 64 + (tid >> 2)) * K + (tid & 3) * 8;

    auto stage = [&](int bufi, int kk) {
        gload16(ga0 + kk, &As[bufi][wave * 512]);
        gload16(ga1 + kk, &As[bufi][2048 + wave * 512]);
        gload16(gb0 + kk, &Bs[bufi][wave * 512]);
        gload16(gb1 + kk, &Bs[bufi][2048 + wave * 512]);
    };
    auto compute = [&](int bufi) {
        short8 af[4], bfr[4];
#pragma unroll
        for (int i = 0; i < 4; i++)
            af[i] = *(short8*)&As[bufi][(wm + i * 16 + l15) * 32 + quad * 8];
#pragma unroll
        for (int j = 0; j < 4; j++)
            bfr[j] = *(short8*)&Bs[bufi][(wn + j * 16 + l15) * 32 + quad * 8];
#pragma unroll
        for (int i = 0; i < 4; i++)
#pragma unroll
            for (int j = 0; j < 4; j++)
                acc[i][j] = __builtin_amdgcn_mfma_f32_16x16x32_bf16(af[i], bfr[j], acc[i][j], 0, 0, 0);
    };

    stage(0, 0);
    int buf = 0;
    for (int t = 0; t < 23; t++) {
        stage(buf ^ 1, (t + 1) * 32);
        asm volatile("s_waitcnt vmcnt(4)" ::: "memory");
        __builtin_amdgcn_s_barrier();
        __builtin_amdgcn_sched_barrier(0);
        compute(buf);
        asm volatile("" ::: "memory");
        __builtin_amdgcn_s_barrier();
        buf ^= 1;
    }
    asm volatile("s_waitcnt vmcnt(0)" ::: "memory");
    __builtin_amdgcn_s_barrier();
    __builtin_amdgcn_sched_barrier(0);
    compute(buf);

#pragma unroll
    for (int j = 0; j < 4; j++) {
        int col = n0 + wn + j * 16 + l15;
#pragma unroll
        for (int i = 0; i < 4; i++) {
#pragma unroll
            for (int rr = 0; rr < 4; rr++) {
                int m = m0 + wm + i * 16 + quad * 4 + rr;
                out[(size_t)m * 768 + col] = acc[i][j][rr];
            }
        }
    }
}

extern "C" void kernel_launch(void* const* d_in, const int* in_sizes, int n_in,
                              void* d_out, int out_size, void* d_ws, size_t ws_size,
                              hipStream_t stream) {
    const float* x = (const float*)d_in[0];
    const float* qkvw = (const float*)d_in[1];
    const float* outw = (const float*)d_in[2];
    const float* aq = (const float*)d_in[3];
    const float* wlp = (const float*)d_in[4];
    const float* wsp = (const float*)d_in[5];
    const float* wgp = (const float*)d_in[6];

    float* ws = (float*)d_ws;
    const size_t NBH = (size_t)B_ * H_ * S_ * HD;  // 6,291,456
    // [0, 1.5*NBH floats): bf16 qfb / kfb / vvb (NBH ushorts each)
    unsigned short* qfb = (unsigned short*)ws;
    unsigned short* kfb = (unsigned short*)(ws + NBH / 2);
    unsigned short* vvb = (unsigned short*)(ws + NBH);
    // attn_region: 2*NBH floats (pkv for 1536 chunks = 1536*8192 = 2*NBH exactly)
    float* attn_region = ws + 3 * NBH / 2;
    //  [0, 3145728)  xb (bf16 x)      : convert .. qkv_gemm
    //  [3145728, 4030464) wb (bf16 qkv_w): convert .. qkv_gemm
    //  [0, 2*NBH)    pkv              : band_partial .. band_reduce
    //  [0, 3145728)  attnb (bf16 attn): combine .. out_gemm
    unsigned short* xb = (unsigned short*)attn_region;
    unsigned short* wb = (unsigned short*)(attn_region + 3145728);
    float* pkv = attn_region;
    unsigned short* attnb = (unsigned short*)attn_region;
    // small buffers past attn_region end:
    float* small = attn_region + 2 * NBH;
    unsigned short* kvsTb = (unsigned short*)small;                 // 48*4096
    unsigned short* ksumsb = kvsTb + 48 * 4096;                     // 48*64
    unsigned short* aoutTb = ksumsb + 48 * 64;                      // 48*768
    unsigned short* aqfb_g = aoutTb + 48 * 768;                     // 9216
    // total ushorts above = 245760 -> 122880 floats
    float* pks = small + 122880;                                    // 1536*128 floats
    unsigned short* outwb = (unsigned short*)(pks + 1536 * 128);

    convert_all<<<8484, 256, 0, stream>>>(x, qkvw, outw, aq, xb, wb, outwb, aqfb_g);
    qkv_gemm_mfma<<<1152, 256, 0, stream>>>(xb, wb, qfb, kfb, vvb);
    band_partial<<<48 * 32, 256, 0, stream>>>(kfb, vvb, pkv, pks);
    band_reduce<<<48 * 4, 256, 0, stream>>>(pkv, pks, aq, kvsTb, ksumsb, aoutTb);
    combine<<<48 * 32, 256, 0, stream>>>(qfb, kfb, vvb, aqfb_g, kvsTb, ksumsb, aoutTb,
                                         wlp, wsp, wgp, attnb);
    out_gemm_mfma<<<384, 256, 0, stream>>>(attnb, outwb, (float*)d_out);
}

// Round 12
// 254.682 us; speedup vs baseline: 1.1092x; 1.1092x over previous
//
#include <hip/hip_runtime.h>
#include <hip/hip_bf16.h>

#define B_ 4
#define S_ 2048
#define D_ 768
#define H_ 12
#define HD 64

typedef __attribute__((ext_vector_type(8))) short short8;
typedef __attribute__((ext_vector_type(4))) float f32x4;

__device__ __forceinline__ float fmapf(float x) { return x > 0.f ? x + 1.f : __expf(x); }

// fp32 -> bf16 round-to-nearest-even (finite inputs only)
__device__ __forceinline__ unsigned short f2bu(float f) {
    unsigned u = __float_as_uint(f);
    u += 0x7FFFu + ((u >> 16) & 1u);
    return (unsigned short)(u >> 16);
}
__device__ __forceinline__ float bu2f(unsigned short v) {
    return __uint_as_float((unsigned)v << 16);
}

// async global->LDS direct copy, 16B per lane. lds ptr must be wave-uniform;
// HW writes lane l to ldsbase + l*16 (m97 pattern: linear LDS dest).
__device__ __forceinline__ void gload16(const void* g, void* l) {
    __builtin_amdgcn_global_load_lds((__attribute__((address_space(1))) void*)(size_t)g,
                                     (__attribute__((address_space(3))) void*)l, 16, 0, 0);
}

union u16x8 {
    uint4 u;
    short8 s;
    unsigned short h[8];
};

// ---------------------------------------------------------------------------
// Kernel 0: fused fp32->bf16 converts for x, qkv_w, out_w + fmap(anchor_q).
// ---------------------------------------------------------------------------
__global__ __launch_bounds__(256) void convert_all(const float* __restrict__ x,
                                                   const float* __restrict__ qkvw,
                                                   const float* __restrict__ outw,
                                                   const float* __restrict__ aq,
                                                   unsigned short* __restrict__ xb,
                                                   unsigned short* __restrict__ wb,
                                                   unsigned short* __restrict__ outwb,
                                                   unsigned short* __restrict__ aqfb_g) {
    int gid = blockIdx.x * 256 + threadIdx.x;
    const float* src;
    unsigned short* dst;
    int i4;
    if (gid < 1572864) {
        src = x; dst = xb; i4 = gid;
    } else if (gid < 1572864 + 442368) {
        src = qkvw; dst = wb; i4 = gid - 1572864;
    } else if (gid < 2162688) {
        src = outw; dst = outwb; i4 = gid - (1572864 + 442368);
    } else {
        int i = gid - 2162688;  // < 9216
        aqfb_g[i] = f2bu(fmapf(aq[i]));
        return;
    }
    float4 v = *(const float4*)&src[i4 * 4];
    ushort4 o;
    o.x = f2bu(v.x); o.y = f2bu(v.y); o.z = f2bu(v.z); o.w = f2bu(v.w);
    *(ushort4*)&dst[i4 * 4] = o;
}

// ---------------------------------------------------------------------------
// Kernel 1: qkv = x @ qkv_w.T via bf16 MFMA. dbuf + XCD swizzle + counted
// vmcnt + LDS-transposed coalesced bf16 epilogue (unchanged from round 10).
// ---------------------------------------------------------------------------
__global__ __launch_bounds__(256) void qkv_gemm_mfma(const unsigned short* __restrict__ xb,
                                                     const unsigned short* __restrict__ wb,
                                                     unsigned short* __restrict__ qfb,
                                                     unsigned short* __restrict__ kfb,
                                                     unsigned short* __restrict__ vvb) {
    __shared__ __attribute__((aligned(16))) unsigned short shmem[18432];
    const int K = 768;
    int orig = blockIdx.x;
    int swz = (orig & 7) * 144 + (orig >> 3);
    int mt = swz / 18, nt = swz - mt * 18;
    int n0 = nt * 128, m0 = mt * 128;
    int tid = threadIdx.x, lane = tid & 63, wave = tid >> 6;
    int wm = (wave & 1) * 64, wn = (wave >> 1) * 64;
    int quad = lane >> 4, l15 = lane & 15;
    f32x4 acc[4][4];
#pragma unroll
    for (int i = 0; i < 4; i++)
#pragma unroll
        for (int j = 0; j < 4; j++) acc[i][j] = 0.f;

    const unsigned short* ga0 = xb + (size_t)(m0 + (tid >> 2)) * K + (tid & 3) * 8;
    const unsigned short* ga1 = xb + (size_t)(m0 + 64 + (tid >> 2)) * K + (tid & 3) * 8;
    const unsigned short* gb0 = wb + (size_t)(n0 + (tid >> 2)) * K + (tid & 3) * 8;
    const unsigned short* gb1 = wb + (size_t)(n0 + 64 + (tid >> 2)) * K + (tid & 3) * 8;

    auto stage = [&](int bufi, int kk) {
        gload16(ga0 + kk, shmem + bufi * 4096 + wave * 512);
        gload16(ga1 + kk, shmem + bufi * 4096 + 2048 + wave * 512);
        gload16(gb0 + kk, shmem + 8192 + bufi * 4096 + wave * 512);
        gload16(gb1 + kk, shmem + 8192 + bufi * 4096 + 2048 + wave * 512);
    };
    auto compute = [&](int bufi) {
        short8 af[4], bfr[4];
#pragma unroll
        for (int i = 0; i < 4; i++)
            af[i] = *(short8*)&shmem[bufi * 4096 + (wm + i * 16 + l15) * 32 + quad * 8];
#pragma unroll
        for (int j = 0; j < 4; j++)
            bfr[j] = *(short8*)&shmem[8192 + bufi * 4096 + (wn + j * 16 + l15) * 32 + quad * 8];
#pragma unroll
        for (int i = 0; i < 4; i++)
#pragma unroll
            for (int j = 0; j < 4; j++)
                acc[i][j] = __builtin_amdgcn_mfma_f32_16x16x32_bf16(af[i], bfr[j], acc[i][j], 0, 0, 0);
    };

    stage(0, 0);
    int buf = 0;
    for (int t = 0; t < 23; t++) {
        stage(buf ^ 1, (t + 1) * 32);
        asm volatile("s_waitcnt vmcnt(4)" ::: "memory");
        __builtin_amdgcn_s_barrier();
        __builtin_amdgcn_sched_barrier(0);
        compute(buf);
        asm volatile("" ::: "memory");
        __builtin_amdgcn_s_barrier();
        buf ^= 1;
    }
    asm volatile("s_waitcnt vmcnt(0)" ::: "memory");
    __builtin_amdgcn_s_barrier();
    __builtin_amdgcn_sched_barrier(0);
    compute(buf);

    // ---- epilogue: LDS-transposed coalesced store ----
    __syncthreads();
    {
        int colbase = n0 + wn;            // 64-aligned -> t3, h wave-uniform
        int t3 = colbase / 768;
        int r = colbase - t3 * 768;
        int h = r >> 6;
        int mstart = m0 + wm;
        int bb = mstart >> 11, sstart = mstart & 2047;
        unsigned short* ldsw = shmem + wave * 4608;  // [64 tok][72]
#pragma unroll
        for (int j = 0; j < 4; j++)
#pragma unroll
            for (int i = 0; i < 4; i++)
#pragma unroll
                for (int rr = 0; rr < 4; rr++) {
                    float val = acc[i][j][rr];
                    unsigned short o = (t3 == 2) ? f2bu(val) : f2bu(fmapf(val));
                    ldsw[(i * 16 + quad * 4 + rr) * 72 + j * 16 + l15] = o;
                }
        unsigned short* gb = (t3 == 0 ? qfb : (t3 == 1 ? kfb : vvb)) +
                             (((size_t)(bb * H_ + h) * S_) + sstart) * (size_t)HD;
#pragma unroll
        for (int c = 0; c < 8; c++) {
            int tok = c * 8 + (lane >> 3);
            uint4 vd = *(uint4*)&ldsw[tok * 72 + (lane & 7) * 8];
            *(uint4*)&gb[(size_t)tok * 64 + (lane & 7) * 8] = vd;
        }
    }
}

// ---------------------------------------------------------------------------
// Kernel 2a: partial kv states — pure streaming. Grid = 48 bh * 16 chunks
// (128 tokens) with 512-thread blocks (8 waves): thread owns 8 e-cols, so
// 24 waves/CU of TLP at the SAME partial count/write traffic as round 10.
// Per-(d,e) accumulation order unchanged -> bit-identical results.
// ---------------------------------------------------------------------------
__global__ __launch_bounds__(512) void band_partial(const unsigned short* __restrict__ kfb,
                                                    const unsigned short* __restrict__ vvb,
                                                    float* __restrict__ pkv,
                                                    float* __restrict__ pks) {
    int bh = blockIdx.x >> 4, chunk = blockIdx.x & 15;
    int sbase = chunk * 128;
    const unsigned short* kfp = kfb + (size_t)bh * S_ * HD + (size_t)sbase * HD;
    const unsigned short* vp = vvb + (size_t)bh * S_ * HD + (size_t)sbase * HD;
    int tid = threadIdx.x;
    int d = tid & 63, eg = tid >> 6, e0 = eg * 8;
    float accg[8], accs[8];
#pragma unroll
    for (int i = 0; i < 8; i++) { accg[i] = 0.f; accs[i] = 0.f; }
    float ksg = 0.f, kss = 0.f;
#pragma unroll 4
    for (int s = 0; s < 128; s++) {
        float kd = bu2f(kfp[(size_t)s * HD + d]);
        bool str = ((sbase + s) % 3) == 0;
        ksg += kd;
        u16x8 va;
        va.u = *(const uint4*)&vp[(size_t)s * HD + e0];
        float vf[8];
#pragma unroll
        for (int i = 0; i < 8; i++) vf[i] = bu2f(va.h[i]);
#pragma unroll
        for (int i = 0; i < 8; i++) accg[i] += kd * vf[i];
        if (str) {
            kss += kd;
#pragma unroll
            for (int i = 0; i < 8; i++) accs[i] += kd * vf[i];
        }
    }
    float* pg = pkv + (size_t)blockIdx.x * 2 * 4096;
#pragma unroll
    for (int i = 0; i < 8; i++) pg[d * 64 + e0 + i] = accg[i];
#pragma unroll
    for (int i = 0; i < 8; i++) pg[4096 + d * 64 + e0 + i] = accs[i];
    if (eg == 0) {
        pks[blockIdx.x * 128 + d] = ksg;
        pks[blockIdx.x * 128 + 64 + d] = kss;
    }
}

// ---------------------------------------------------------------------------
// Kernel 2b: reduce partials (16/bh) + anchor outputs. Grid = 48*4.
// ---------------------------------------------------------------------------
__global__ __launch_bounds__(256) void band_reduce(const float* __restrict__ pkv,
                                                   const float* __restrict__ pks,
                                                   const float* __restrict__ aq,
                                                   unsigned short* __restrict__ kvsTb,
                                                   unsigned short* __restrict__ ksumsb,
                                                   unsigned short* __restrict__ aoutTb) {
    int bh = blockIdx.x >> 2, eb = blockIdx.x & 3, e0 = eb * 16;
    int h = bh % H_;
    __shared__ float kvgL[64][17];
    __shared__ float ksgL[64];
    __shared__ float anorm[12];
    int tid = threadIdx.x;
    for (int idx = tid; idx < 1024; idx += 256) {
        int d = idx >> 4, j = idx & 15;
        float sg = 0.f, ss = 0.f;
        const float* p = pkv + (size_t)(bh * 16) * 2 * 4096 + d * 64 + e0 + j;
#pragma unroll 4
        for (int c = 0; c < 16; c++) {
            sg += p[0];
            ss += p[4096];
            p += 2 * 4096;
        }
        kvgL[d][j] = sg;
        kvsTb[(size_t)bh * 4096 + (e0 + j) * 64 + d] = f2bu(ss);
    }
    if (tid < 64) {
        float sg = 0.f, ss = 0.f;
#pragma unroll 4
        for (int c = 0; c < 16; c++) {
            sg += pks[(bh * 16 + c) * 128 + tid];
            ss += pks[(bh * 16 + c) * 128 + 64 + tid];
        }
        ksgL[tid] = sg;
        if (eb == 0) ksumsb[bh * 64 + tid] = f2bu(ss);
    }
    __syncthreads();
    if (tid < 12) {
        float nrm = 0.f;
        for (int dd = 0; dd < 64; dd++)
            nrm += fmapf(aq[h * 768 + tid * 64 + dd]) * ksgL[dd];
        anorm[tid] = fmaxf(nrm, 1e-6f);
    }
    __syncthreads();
    if (tid < 192) {
        int a = tid >> 4, j = tid & 15;
        float acc = 0.f;
        for (int dd = 0; dd < 64; dd++)
            acc += fmapf(aq[h * 768 + a * 64 + dd]) * kvgL[dd][j];
        aoutTb[(size_t)bh * 768 + (e0 + j) * 12 + a] = f2bu(acc / anorm[a]);
    }
}

// ---------------------------------------------------------------------------
// Kernel 3: combine — register-direct MFMA fragments (unchanged).
// ---------------------------------------------------------------------------
__global__ __launch_bounds__(256) void combine(const unsigned short* __restrict__ qfb,
                                               const unsigned short* __restrict__ kfb,
                                               const unsigned short* __restrict__ vvb,
                                               const unsigned short* __restrict__ aqfb_g,
                                               const unsigned short* __restrict__ kvsTb,
                                               const unsigned short* __restrict__ ksumsb,
                                               const unsigned short* __restrict__ aoutTb,
                                               const float* __restrict__ wlp,
                                               const float* __restrict__ wsp,
                                               const float* __restrict__ wgp,
                                               unsigned short* __restrict__ attnb) {
    __shared__ __attribute__((aligned(16))) unsigned short aqfb[16][72];   // anchors + ksum
    __shared__ __attribute__((aligned(16))) unsigned short vtbT[64][104];  // [e][band k], k<96
    __shared__ __attribute__((aligned(16))) unsigned short plb[64][104];   // masked P
    __shared__ __attribute__((aligned(16))) unsigned short qkgb[64][40];   // [token][anchor k]
    __shared__ float nrm[4][3][16];
    int bh = blockIdx.x >> 5, stile = blockIdx.x & 31;
    int b = bh / H_, h = bh % H_;
    int s0 = stile * 64;
    int tid = threadIdx.x, lane = tid & 63, wave = tid >> 6;
    int quad = lane >> 4, l15 = lane & 15;
    const unsigned short* qfp = qfb + (size_t)bh * S_ * HD;
    const unsigned short* kfp = kfb + (size_t)bh * S_ * HD;
    const unsigned short* vp = vvb + (size_t)bh * S_ * HD;
    float a0 = wlp[0], a1 = wsp[0], a2 = wgp[0];
    float mx = fmaxf(a0, fmaxf(a1, a2));
    float ew0 = __expf(a0 - mx), ew1 = __expf(a1 - mx), ew2 = __expf(a2 - mx);
    float inv = 1.f / (ew0 + ew1 + ew2);
    float wl = ew0 * inv, wsb = ew1 * inv, wg = ew2 * inv;
    // ---- stage: vtbT (bf16 copy transpose), aqfb, K-pads ----
    for (int i = tid; i < 96 * 64; i += 256) {
        int k = i >> 6, e = i & 63;
        int gs = s0 + k - 6;
        unsigned short v_ = (k < 75 && gs >= 0 && gs < S_) ? vp[(size_t)gs * HD + e]
                                                           : (unsigned short)0;
        vtbT[e][k] = v_;
    }
    if (tid < 192) {
        int a = tid >> 4, c = (tid & 15) * 4;
        *(ushort4*)&aqfb[a][c] = *(const ushort4*)&aqfb_g[h * 768 + a * 64 + c];
    }
    if (tid < 64) aqfb[12][tid] = ksumsb[bh * 64 + tid];
    if (tid < 192) aqfb[13 + (tid >> 6)][tid & 63] = 0;
    for (int i = tid; i < 1024; i += 256) {
        plb[i >> 4][80 + (i & 15)] = 0;   // K-pad cols 80..95
        qkgb[i >> 4][16 + (i & 15)] = 0;  // K-pad cols 16..31
    }
    __syncthreads();
    // ---- q A-fragments: per-thread rows, loaded once, reused everywhere ----
    u16x8 qa0, qa1;
    {
        const unsigned short* qr = qfp + (size_t)(s0 + wave * 16 + l15) * HD + quad * 8;
        qa0.u = *(const uint4*)qr;
        qa1.u = *(const uint4*)(qr + 32);
    }
    // ---- phase A: wave w computes P rows w*16..w*16+15 (wave-private) ----
#pragma unroll
    for (int tj = 0; tj < 5; tj++) {
        int row = tj * 16 + l15;
        int gs = s0 + row - 6;
        bool valid = (row < 75) && (gs >= 0) && (gs < S_);
        int gsc = gs < 0 ? 0 : (gs > S_ - 1 ? S_ - 1 : gs);
        const unsigned short* kr = kfp + (size_t)gsc * HD + quad * 8;
        u16x8 b0, b1, ones;
        ones.u = make_uint4(0x3F803F80u, 0x3F803F80u, 0x3F803F80u, 0x3F803F80u);
        b0.u = *(const uint4*)kr;
        b1.u = *(const uint4*)(kr + 32);
        if (!valid) { b0 = ones; b1 = ones; }
        f32x4 c = {0.f, 0.f, 0.f, 0.f};
        c = __builtin_amdgcn_mfma_f32_16x16x32_bf16(qa0.s, b0.s, c, 0, 0, 0);
        c = __builtin_amdgcn_mfma_f32_16x16x32_bf16(qa1.s, b1.s, c, 0, 0, 0);
        int col = tj * 16 + l15;
#pragma unroll
        for (int rr = 0; rr < 4; rr++) {
            int tok = wave * 16 + quad * 4 + rr;
            int which = col - tok;
            plb[tok][col] = (which >= 0 && which < 12) ? f2bu(c[rr]) : (unsigned short)0;
        }
    }
    {
        f32x4 c = {0.f, 0.f, 0.f, 0.f};
        short8 bfr0 = *(short8*)&aqfb[l15][quad * 8];
        short8 bfr1 = *(short8*)&aqfb[l15][32 + quad * 8];
        c = __builtin_amdgcn_mfma_f32_16x16x32_bf16(qa0.s, bfr0, c, 0, 0, 0);
        c = __builtin_amdgcn_mfma_f32_16x16x32_bf16(qa1.s, bfr1, c, 0, 0, 0);
#pragma unroll
        for (int rr = 0; rr < 4; rr++) qkgb[wave * 16 + quad * 4 + rr][l15] = f2bu(c[rr]);
    }
    // ---- per-wave norms -> reciprocal combine weights (lanes 0-15) ----
    if (lane < 16) {
        int t = wave * 16 + lane;
        float sl = 0.f;
#pragma unroll
        for (int j = 0; j < 12; j++) sl += bu2f(plb[t][t + j]);
        float sg = 0.f;
#pragma unroll
        for (int a = 0; a < 12; a++) sg += bu2f(qkgb[t][a]);
        nrm[wave][0][lane] = wl / fmaxf(sl, 1e-6f);
        nrm[wave][1][lane] = wg / fmaxf(sg, 1e-6f);
        nrm[wave][2][lane] = wsb / fmaxf(bu2f(qkgb[t][12]), 1e-6f);
    }
    // ---- phase B: fused MFMA; B-frags for stride/global bands direct ----
#pragma unroll
    for (int j2 = 0; j2 < 4; j2++) {
        int e = j2 * 16 + l15;
        f32x4 cL = {0.f, 0.f, 0.f, 0.f};
        f32x4 cG = {0.f, 0.f, 0.f, 0.f};
        f32x4 cS = {0.f, 0.f, 0.f, 0.f};
#pragma unroll
        for (int kk = 0; kk < 3; kk++) {
            short8 afr = *(short8*)&plb[wave * 16 + l15][kk * 32 + quad * 8];
            short8 bfr = *(short8*)&vtbT[e][kk * 32 + quad * 8];
            cL = __builtin_amdgcn_mfma_f32_16x16x32_bf16(afr, bfr, cL, 0, 0, 0);
        }
        {
            short8 afr = *(short8*)&qkgb[wave * 16 + l15][quad * 8];
            u16x8 bo;
            bo.u = make_uint4(0u, 0u, 0u, 0u);
            const unsigned* ap = (const unsigned*)(aoutTb + (size_t)bh * 768 + e * 12);
            if (quad == 0) {
                bo.u.x = ap[0]; bo.u.y = ap[1]; bo.u.z = ap[2]; bo.u.w = ap[3];
            } else if (quad == 1) {
                bo.u.x = ap[4]; bo.u.y = ap[5];
            }
            cG = __builtin_amdgcn_mfma_f32_16x16x32_bf16(afr, bo.s, cG, 0, 0, 0);
        }
        {
            const unsigned short* kvp = kvsTb + (size_t)bh * 4096 + e * 64 + quad * 8;
            u16x8 bk0, bk1;
            bk0.u = *(const uint4*)kvp;
            bk1.u = *(const uint4*)(kvp + 32);
            cS = __builtin_amdgcn_mfma_f32_16x16x32_bf16(qa0.s, bk0.s, cS, 0, 0, 0);
            cS = __builtin_amdgcn_mfma_f32_16x16x32_bf16(qa1.s, bk1.s, cS, 0, 0, 0);
        }
#pragma unroll
        for (int rr = 0; rr < 4; rr++) {
            int tq = quad * 4 + rr;
            int tok = wave * 16 + tq;
            float res = cL[rr] * nrm[wave][0][tq] + cS[rr] * nrm[wave][2][tq] +
                        cG[rr] * nrm[wave][1][tq];
            attnb[((size_t)(b * S_ + s0 + tok)) * 768 + h * 64 + e] = f2bu(res);
        }
    }
}

// ---------------------------------------------------------------------------
// Kernel 4: out = attn(bf16) @ out_w.T, counted-vmcnt dbuf + XCD swizzle.
// ---------------------------------------------------------------------------
__global__ __launch_bounds__(256) void out_gemm_mfma(const unsigned short* __restrict__ attnb,
                                                     const unsigned short* __restrict__ wb,
                                                     float* __restrict__ out) {
    __shared__ __attribute__((aligned(16))) unsigned short As[2][128 * 32];
    __shared__ __attribute__((aligned(16))) unsigned short Bs[2][128 * 32];
    const int K = 768;
    int orig = blockIdx.x;
    int swz = (orig & 7) * 48 + (orig >> 3);
    int mt = swz / 6, nt = swz - mt * 6;
    int n0 = nt * 128, m0 = mt * 128;
    int tid = threadIdx.x, lane = tid & 63, wave = tid >> 6;
    int wm = (wave & 1) * 64, wn = (wave >> 1) * 64;
    int quad = lane >> 4, l15 = lane & 15;
    f32x4 acc[4][4];
#pragma unroll
    for (int i = 0; i < 4; i++)
#pragma unroll
        for (int j = 0; j < 4; j++) acc[i][j] = 0.f;

    const unsigned short* ga0 = attnb + (size_t)(m0 + (tid >> 2)) * K + (tid & 3) * 8;
    const unsigned short* ga1 = attnb + (size_t)(m0 + 64 + (tid >> 2)) * K + (tid & 3) * 8;
    const unsigned short* gb0 = wb + (size_t)(n0 + (tid >> 2)) * K + (tid & 3) * 8;
    const unsigned short* gb1 = wb + (size_t)(n0 + 64 + (tid >> 2)) * K + (tid & 3) * 8;

    auto stage = [&](int bufi, int kk) {
        gload16(ga0 + kk, &As[bufi][wave * 512]);
        gload16(ga1 + kk, &As[bufi][2048 + wave * 512]);
        gload16(gb0 + kk, &Bs[bufi][wave * 512]);
        gload16(gb1 + kk, &Bs[bufi][2048 + wave * 512]);
    };
    auto compute = [&](int bufi) {
        short8 af[4], bfr[4];
#pragma unroll
        for (int i = 0; i < 4; i++)
            af[i] = *(short8*)&As[bufi][(wm + i * 16 + l15) * 32 + quad * 8];
#pragma unroll
        for (int j = 0; j < 4; j++)
            bfr[j] = *(short8*)&Bs[bufi][(wn + j * 16 + l15) * 32 + quad * 8];
#pragma unroll
        for (int i = 0; i < 4; i++)
#pragma unroll
            for (int j = 0; j < 4; j++)
                acc[i][j] = __builtin_amdgcn_mfma_f32_16x16x32_bf16(af[i], bfr[j], acc[i][j], 0, 0, 0);
    };

    stage(0, 0);
    int buf = 0;
    for (int t = 0; t < 23; t++) {
        stage(buf ^ 1, (t + 1) * 32);
        asm volatile("s_waitcnt vmcnt(4)" ::: "memory");
        __builtin_amdgcn_s_barrier();
        __builtin_amdgcn_sched_barrier(0);
        compute(buf);
        asm volatile("" ::: "memory");
        __builtin_amdgcn_s_barrier();
        buf ^= 1;
    }
    asm volatile("s_waitcnt vmcnt(0)" ::: "memory");
    __builtin_amdgcn_s_barrier();
    __builtin_amdgcn_sched_barrier(0);
    compute(buf);

#pragma unroll
    for (int j = 0; j < 4; j++) {
        int col = n0 + wn + j * 16 + l15;
#pragma unroll
        for (int i = 0; i < 4; i++) {
#pragma unroll
            for (int rr = 0; rr < 4; rr++) {
                int m = m0 + wm + i * 16 + quad * 4 + rr;
                out[(size_t)m * 768 + col] = acc[i][j][rr];
            }
        }
    }
}

extern "C" void kernel_launch(void* const* d_in, const int* in_sizes, int n_in,
                              void* d_out, int out_size, void* d_ws, size_t ws_size,
                              hipStream_t stream) {
    const float* x = (const float*)d_in[0];
    const float* qkvw = (const float*)d_in[1];
    const float* outw = (const float*)d_in[2];
    const float* aq = (const float*)d_in[3];
    const float* wlp = (const float*)d_in[4];
    const float* wsp = (const float*)d_in[5];
    const float* wgp = (const float*)d_in[6];

    float* ws = (float*)d_ws;
    const size_t NBH = (size_t)B_ * H_ * S_ * HD;  // 6,291,456
    // [0, 1.5*NBH floats): bf16 qfb / kfb / vvb (NBH ushorts each)
    unsigned short* qfb = (unsigned short*)ws;
    unsigned short* kfb = (unsigned short*)(ws + NBH / 2);
    unsigned short* vvb = (unsigned short*)(ws + NBH);
    float* attn_region = ws + 2 * NBH;  // NBH floats; multi-use scratch
    unsigned short* xb = (unsigned short*)attn_region;
    unsigned short* wb = (unsigned short*)(attn_region + 3145728);
    float* pkv = attn_region;
    unsigned short* attnb = (unsigned short*)attn_region;
    unsigned short* kvsTb = (unsigned short*)(attn_region + NBH);   // 48*4096
    unsigned short* ksumsb = kvsTb + 48 * 4096;                     // 48*64
    unsigned short* aoutTb = ksumsb + 48 * 64;                      // 48*768
    unsigned short* aqfb_g = aoutTb + 48 * 768;                     // 9216
    float* pks = attn_region + NBH + 122880;                        // 768*128 floats
    unsigned short* outwb = (unsigned short*)(pks + 768 * 128);

    convert_all<<<8484, 256, 0, stream>>>(x, qkvw, outw, aq, xb, wb, outwb, aqfb_g);
    qkv_gemm_mfma<<<1152, 256, 0, stream>>>(xb, wb, qfb, kfb, vvb);
    band_partial<<<48 * 16, 512, 0, stream>>>(kfb, vvb, pkv, pks);
    band_reduce<<<48 * 4, 256, 0, stream>>>(pkv, pks, aq, kvsTb, ksumsb, aoutTb);
    combine<<<48 * 32, 256, 0, stream>>>(qfb, kfb, vvb, aqfb_g, kvsTb, ksumsb, aoutTb,
                                         wlp, wsp, wgp, attnb);
    out_gemm_mfma<<<384, 256, 0, stream>>>(attnb, outwb, (float*)d_out);
}

// Round 13
// 218.547 us; speedup vs baseline: 1.2926x; 1.1653x over previous
//
#include <hip/hip_runtime.h>
#include <hip/hip_bf16.h>

#define B_ 4
#define S_ 2048
#define D_ 768
#define H_ 12
#define HD 64

typedef __attribute__((ext_vector_type(8))) short short8;
typedef __attribute__((ext_vector_type(4))) float f32x4;

__device__ __forceinline__ float fmapf(float x) { return x > 0.f ? x + 1.f : __expf(x); }

// fp32 -> bf16 round-to-nearest-even (finite inputs only)
__device__ __forceinline__ unsigned short f2bu(float f) {
    unsigned u = __float_as_uint(f);
    u += 0x7FFFu + ((u >> 16) & 1u);
    return (unsigned short)(u >> 16);
}
__device__ __forceinline__ float bu2f(unsigned short v) {
    return __uint_as_float((unsigned)v << 16);
}

// async global->LDS direct copy, 16B per lane. lds ptr must be wave-uniform;
// HW writes lane l to ldsbase + l*16 (m97 pattern: linear LDS dest).
__device__ __forceinline__ void gload16(const void* g, void* l) {
    __builtin_amdgcn_global_load_lds((__attribute__((address_space(1))) void*)(size_t)g,
                                     (__attribute__((address_space(3))) void*)l, 16, 0, 0);
}

union u16x8 {
    uint4 u;
    short8 s;
    unsigned short h[8];
};

// ---------------------------------------------------------------------------
// Kernel 0: fused fp32->bf16 converts for x, qkv_w, out_w + fmap(anchor_q).
// ---------------------------------------------------------------------------
__global__ __launch_bounds__(256) void convert_all(const float* __restrict__ x,
                                                   const float* __restrict__ qkvw,
                                                   const float* __restrict__ outw,
                                                   const float* __restrict__ aq,
                                                   unsigned short* __restrict__ xb,
                                                   unsigned short* __restrict__ wb,
                                                   unsigned short* __restrict__ outwb,
                                                   unsigned short* __restrict__ aqfb_g) {
    int gid = blockIdx.x * 256 + threadIdx.x;
    const float* src;
    unsigned short* dst;
    int i4;
    if (gid < 1572864) {
        src = x; dst = xb; i4 = gid;
    } else if (gid < 1572864 + 442368) {
        src = qkvw; dst = wb; i4 = gid - 1572864;
    } else if (gid < 2162688) {
        src = outw; dst = outwb; i4 = gid - (1572864 + 442368);
    } else {
        int i = gid - 2162688;  // < 9216
        aqfb_g[i] = f2bu(fmapf(aq[i]));
        return;
    }
    float4 v = *(const float4*)&src[i4 * 4];
    ushort4 o;
    o.x = f2bu(v.x); o.y = f2bu(v.y); o.z = f2bu(v.z); o.w = f2bu(v.w);
    *(ushort4*)&dst[i4 * 4] = o;
}

// ---------------------------------------------------------------------------
// Kernel 1: qkv = x @ qkv_w.T via bf16 MFMA. dbuf + XCD swizzle + counted
// vmcnt + LDS-staged coalesced epilogue. Per 64x64 wave-tile t3/h are
// wave-uniform. Outputs: q -> qfb [s][d]; k -> kfb [s][d] AND kTb [d][s];
// v -> vTb [d][s] only. Transposed stores are 64 s contiguous per d-row
// (full cache lines).
// ---------------------------------------------------------------------------
__global__ __launch_bounds__(256) void qkv_gemm_mfma(const unsigned short* __restrict__ xb,
                                                     const unsigned short* __restrict__ wb,
                                                     unsigned short* __restrict__ qfb,
                                                     unsigned short* __restrict__ kfb,
                                                     unsigned short* __restrict__ kTb,
                                                     unsigned short* __restrict__ vTb) {
    __shared__ __attribute__((aligned(16))) unsigned short shmem[18432];
    const int K = 768;
    int orig = blockIdx.x;
    int swz = (orig & 7) * 144 + (orig >> 3);
    int mt = swz / 18, nt = swz - mt * 18;
    int n0 = nt * 128, m0 = mt * 128;
    int tid = threadIdx.x, lane = tid & 63, wave = tid >> 6;
    int wm = (wave & 1) * 64, wn = (wave >> 1) * 64;
    int quad = lane >> 4, l15 = lane & 15;
    f32x4 acc[4][4];
#pragma unroll
    for (int i = 0; i < 4; i++)
#pragma unroll
        for (int j = 0; j < 4; j++) acc[i][j] = 0.f;

    const unsigned short* ga0 = xb + (size_t)(m0 + (tid >> 2)) * K + (tid & 3) * 8;
    const unsigned short* ga1 = xb + (size_t)(m0 + 64 + (tid >> 2)) * K + (tid & 3) * 8;
    const unsigned short* gb0 = wb + (size_t)(n0 + (tid >> 2)) * K + (tid & 3) * 8;
    const unsigned short* gb1 = wb + (size_t)(n0 + 64 + (tid >> 2)) * K + (tid & 3) * 8;

    auto stage = [&](int bufi, int kk) {
        gload16(ga0 + kk, shmem + bufi * 4096 + wave * 512);
        gload16(ga1 + kk, shmem + bufi * 4096 + 2048 + wave * 512);
        gload16(gb0 + kk, shmem + 8192 + bufi * 4096 + wave * 512);
        gload16(gb1 + kk, shmem + 8192 + bufi * 4096 + 2048 + wave * 512);
    };
    auto compute = [&](int bufi) {
        short8 af[4], bfr[4];
#pragma unroll
        for (int i = 0; i < 4; i++)
            af[i] = *(short8*)&shmem[bufi * 4096 + (wm + i * 16 + l15) * 32 + quad * 8];
#pragma unroll
        for (int j = 0; j < 4; j++)
            bfr[j] = *(short8*)&shmem[8192 + bufi * 4096 + (wn + j * 16 + l15) * 32 + quad * 8];
#pragma unroll
        for (int i = 0; i < 4; i++)
#pragma unroll
            for (int j = 0; j < 4; j++)
                acc[i][j] = __builtin_amdgcn_mfma_f32_16x16x32_bf16(af[i], bfr[j], acc[i][j], 0, 0, 0);
    };

    stage(0, 0);
    int buf = 0;
    for (int t = 0; t < 23; t++) {
        stage(buf ^ 1, (t + 1) * 32);
        asm volatile("s_waitcnt vmcnt(4)" ::: "memory");
        __builtin_amdgcn_s_barrier();
        __builtin_amdgcn_sched_barrier(0);
        compute(buf);
        asm volatile("" ::: "memory");
        __builtin_amdgcn_s_barrier();
        buf ^= 1;
    }
    asm volatile("s_waitcnt vmcnt(0)" ::: "memory");
    __builtin_amdgcn_s_barrier();
    __builtin_amdgcn_sched_barrier(0);
    compute(buf);

    // ---- epilogue ----
    __syncthreads();  // all waves done reading staging buffers
    {
        int colbase = n0 + wn;            // 64-aligned -> t3, h wave-uniform
        int t3 = colbase / 768;
        int r = colbase - t3 * 768;
        int h = r >> 6;
        int mstart = m0 + wm;
        int bb = mstart >> 11, sstart = mstart & 2047;
        unsigned short* ldsw = shmem + wave * 4608;  // per-wave 64x72 tile
        if (t3 <= 1) {
            // normal [tok][col] fill + coalesced store (q, k)
#pragma unroll
            for (int j = 0; j < 4; j++)
#pragma unroll
                for (int i = 0; i < 4; i++)
#pragma unroll
                    for (int rr = 0; rr < 4; rr++) {
                        float val = acc[i][j][rr];
                        ldsw[(i * 16 + quad * 4 + rr) * 72 + j * 16 + l15] = f2bu(fmapf(val));
                    }
            unsigned short* gbp = (t3 == 0 ? qfb : kfb) +
                                  (((size_t)(bb * H_ + h) * S_) + sstart) * (size_t)HD;
#pragma unroll
            for (int c = 0; c < 8; c++) {
                int tok = c * 8 + (lane >> 3);
                uint4 vd = *(uint4*)&ldsw[tok * 72 + (lane & 7) * 8];
                *(uint4*)&gbp[(size_t)tok * 64 + (lane & 7) * 8] = vd;
            }
        }
        if (t3 >= 1) {
            // transposed [d][tok] fill + coalesced store (k -> kTb, v -> vTb).
            // Per-wave LDS ops are in-order, so refill after the reads is safe.
#pragma unroll
            for (int j = 0; j < 4; j++)
#pragma unroll
                for (int i = 0; i < 4; i++)
#pragma unroll
                    for (int rr = 0; rr < 4; rr++) {
                        float val = acc[i][j][rr];
                        unsigned short o = (t3 == 1) ? f2bu(fmapf(val)) : f2bu(val);
                        ldsw[(j * 16 + l15) * 72 + i * 16 + quad * 4 + rr] = o;
                    }
            unsigned short* gt = (t3 == 1 ? kTb : vTb) +
                                 ((size_t)(bb * H_ + h) * 64) * (size_t)S_ + sstart;
#pragma unroll
            for (int c = 0; c < 8; c++) {
                int d = c * 8 + (lane >> 3);
                uint4 vd = *(uint4*)&ldsw[d * 72 + (lane & 7) * 8];
                *(uint4*)&gt[(size_t)d * S_ + (lane & 7) * 8] = vd;
            }
        }
    }
}

// ---------------------------------------------------------------------------
// Kernel 2a: partial kv states via MFMA. kv[d][e] = sum_s k[s][d] v[s][e] is
// matmul-shaped (contraction over s); kTb/vTb give [row][s] fragments.
// Grid = 48 bh * 16 chunks (128 tokens); 4 waves, wave w owns d-rows
// [16w,16w+16). Stride-band accumulator uses bitmasked A (s%3==0 kept).
// ksums via ones-vector B operand. pkv/pks layout identical to before.
// ---------------------------------------------------------------------------
__global__ __launch_bounds__(256) void band_partial(const unsigned short* __restrict__ kTb,
                                                    const unsigned short* __restrict__ vTb,
                                                    float* __restrict__ pkv,
                                                    float* __restrict__ pks) {
    int bh = blockIdx.x >> 4, chunk = blockIdx.x & 15;
    int s0 = chunk * 128;
    int tid = threadIdx.x, lane = tid & 63, wave = tid >> 6;
    int quad = lane >> 4, l15 = lane & 15;
    const unsigned short* kT = kTb + (size_t)bh * 64 * S_;
    const unsigned short* vT = vTb + (size_t)bh * 64 * S_;
    f32x4 cg[4], cs[4], og, os;
#pragma unroll
    for (int j = 0; j < 4; j++) { cg[j] = 0.f; cs[j] = 0.f; }
    og = 0.f; os = 0.f;
    u16x8 ONES;
    ONES.u = make_uint4(0x3F803F80u, 0x3F803F80u, 0x3F803F80u, 0x3F803F80u);
    // stride masks: element i kept iff (r+i)%3==0, r = s%3 of first element
    const uint4 M0 = make_uint4(0x0000FFFFu, 0xFFFF0000u, 0u, 0x0000FFFFu);
    const uint4 M1 = make_uint4(0u, 0x0000FFFFu, 0xFFFF0000u, 0u);
    const uint4 M2 = make_uint4(0xFFFF0000u, 0u, 0x0000FFFFu, 0xFFFF0000u);
#pragma unroll
    for (int st = 0; st < 4; st++) {
        int sb = s0 + st * 32 + quad * 8;
        u16x8 A;
        A.u = *(const uint4*)&kT[(size_t)(wave * 16 + l15) * S_ + sb];
        int rmod = sb % 3;
        uint4 m = (rmod == 0) ? M0 : ((rmod == 1) ? M1 : M2);
        u16x8 Am;
        Am.u.x = A.u.x & m.x; Am.u.y = A.u.y & m.y;
        Am.u.z = A.u.z & m.z; Am.u.w = A.u.w & m.w;
        og = __builtin_amdgcn_mfma_f32_16x16x32_bf16(A.s, ONES.s, og, 0, 0, 0);
        os = __builtin_amdgcn_mfma_f32_16x16x32_bf16(Am.s, ONES.s, os, 0, 0, 0);
#pragma unroll
        for (int j = 0; j < 4; j++) {
            u16x8 Bf;
            Bf.u = *(const uint4*)&vT[(size_t)(j * 16 + l15) * S_ + sb];
            cg[j] = __builtin_amdgcn_mfma_f32_16x16x32_bf16(A.s, Bf.s, cg[j], 0, 0, 0);
            cs[j] = __builtin_amdgcn_mfma_f32_16x16x32_bf16(Am.s, Bf.s, cs[j], 0, 0, 0);
        }
    }
    float* pg = pkv + (size_t)blockIdx.x * 2 * 4096;
#pragma unroll
    for (int j = 0; j < 4; j++)
#pragma unroll
        for (int rr = 0; rr < 4; rr++) {
            int d = wave * 16 + quad * 4 + rr;
            int e = j * 16 + l15;
            pg[d * 64 + e] = cg[j][rr];
            pg[4096 + d * 64 + e] = cs[j][rr];
        }
    if (l15 == 0) {
#pragma unroll
        for (int rr = 0; rr < 4; rr++) {
            int d = wave * 16 + quad * 4 + rr;
            pks[blockIdx.x * 128 + d] = og[rr];
            pks[blockIdx.x * 128 + 64 + d] = os[rr];
        }
    }
}

// ---------------------------------------------------------------------------
// Kernel 2b: reduce partials (16/bh) + anchor outputs. Grid = 48*4.
// ---------------------------------------------------------------------------
__global__ __launch_bounds__(256) void band_reduce(const float* __restrict__ pkv,
                                                   const float* __restrict__ pks,
                                                   const float* __restrict__ aq,
                                                   unsigned short* __restrict__ kvsTb,
                                                   unsigned short* __restrict__ ksumsb,
                                                   unsigned short* __restrict__ aoutTb) {
    int bh = blockIdx.x >> 2, eb = blockIdx.x & 3, e0 = eb * 16;
    int h = bh % H_;
    __shared__ float kvgL[64][17];
    __shared__ float ksgL[64];
    __shared__ float anorm[12];
    int tid = threadIdx.x;
    for (int idx = tid; idx < 1024; idx += 256) {
        int d = idx >> 4, j = idx & 15;
        float sg = 0.f, ss = 0.f;
        const float* p = pkv + (size_t)(bh * 16) * 2 * 4096 + d * 64 + e0 + j;
#pragma unroll 4
        for (int c = 0; c < 16; c++) {
            sg += p[0];
            ss += p[4096];
            p += 2 * 4096;
        }
        kvgL[d][j] = sg;
        kvsTb[(size_t)bh * 4096 + (e0 + j) * 64 + d] = f2bu(ss);
    }
    if (tid < 64) {
        float sg = 0.f, ss = 0.f;
#pragma unroll 4
        for (int c = 0; c < 16; c++) {
            sg += pks[(bh * 16 + c) * 128 + tid];
            ss += pks[(bh * 16 + c) * 128 + 64 + tid];
        }
        ksgL[tid] = sg;
        if (eb == 0) ksumsb[bh * 64 + tid] = f2bu(ss);
    }
    __syncthreads();
    if (tid < 12) {
        float nrm = 0.f;
        for (int dd = 0; dd < 64; dd++)
            nrm += fmapf(aq[h * 768 + tid * 64 + dd]) * ksgL[dd];
        anorm[tid] = fmaxf(nrm, 1e-6f);
    }
    __syncthreads();
    if (tid < 192) {
        int a = tid >> 4, j = tid & 15;
        float acc = 0.f;
        for (int dd = 0; dd < 64; dd++)
            acc += fmapf(aq[h * 768 + a * 64 + dd]) * kvgL[dd][j];
        aoutTb[(size_t)bh * 768 + (e0 + j) * 12 + a] = f2bu(acc / anorm[a]);
    }
}

// ---------------------------------------------------------------------------
// Kernel 3: combine — register-direct MFMA fragments. vtbT staged by VECTOR
// row copies from vTb (band window shifted +2: col k <-> gs = s0 + k - 8 so
// the copy base s0-8 is 16B-aligned). Band mask: which = col - tok in [2,14).
// ---------------------------------------------------------------------------
__global__ __launch_bounds__(256) void combine(const unsigned short* __restrict__ qfb,
                                               const unsigned short* __restrict__ kfb,
                                               const unsigned short* __restrict__ vTb,
                                               const unsigned short* __restrict__ aqfb_g,
                                               const unsigned short* __restrict__ kvsTb,
                                               const unsigned short* __restrict__ ksumsb,
                                               const unsigned short* __restrict__ aoutTb,
                                               const float* __restrict__ wlp,
                                               const float* __restrict__ wsp,
                                               const float* __restrict__ wgp,
                                               unsigned short* __restrict__ attnb) {
    __shared__ __attribute__((aligned(16))) unsigned short aqfb[16][72];   // anchors + ksum
    __shared__ __attribute__((aligned(16))) unsigned short vtbT[64][104];  // [e][band k], k<96
    __shared__ __attribute__((aligned(16))) unsigned short plb[64][104];   // masked P
    __shared__ __attribute__((aligned(16))) unsigned short qkgb[64][40];   // [token][anchor k]
    __shared__ float nrm[4][3][16];
    int bh = blockIdx.x >> 5, stile = blockIdx.x & 31;
    int b = bh / H_, h = bh % H_;
    int s0 = stile * 64;
    int tid = threadIdx.x, lane = tid & 63, wave = tid >> 6;
    int quad = lane >> 4, l15 = lane & 15;
    const unsigned short* qfp = qfb + (size_t)bh * S_ * HD;
    const unsigned short* kfp = kfb + (size_t)bh * S_ * HD;
    const unsigned short* vTp = vTb + (size_t)bh * 64 * S_;
    float a0 = wlp[0], a1 = wsp[0], a2 = wgp[0];
    float mx = fmaxf(a0, fmaxf(a1, a2));
    float ew0 = __expf(a0 - mx), ew1 = __expf(a1 - mx), ew2 = __expf(a2 - mx);
    float inv = 1.f / (ew0 + ew1 + ew2);
    float wl = ew0 * inv, wsb = ew1 * inv, wg = ew2 * inv;
    // ---- stage: vtbT via vector row copies from vTb; aqfb; K-pads ----
    for (int u = tid; u < 64 * 12; u += 256) {
        int e = u & 63, c = u >> 6;  // c in [0,12): 8-col chunk
        int k0 = c * 8;
        int gs0 = s0 - 8 + k0;
        const unsigned short* src = vTp + (size_t)e * S_ + gs0;
        if (gs0 >= 0 && gs0 + 8 <= S_) {
            *(uint4*)&vtbT[e][k0] = *(const uint4*)src;
        } else {
#pragma unroll
            for (int i = 0; i < 8; i++) {
                int gs = gs0 + i;
                vtbT[e][k0 + i] = (gs >= 0 && gs < S_) ? src[i] : (unsigned short)0;
            }
        }
    }
    if (tid < 192) {
        int a = tid >> 4, c = (tid & 15) * 4;
        *(ushort4*)&aqfb[a][c] = *(const ushort4*)&aqfb_g[h * 768 + a * 64 + c];
    }
    if (tid < 64) aqfb[12][tid] = ksumsb[bh * 64 + tid];
    if (tid < 192) aqfb[13 + (tid >> 6)][tid & 63] = 0;
    for (int i = tid; i < 1024; i += 256) {
        plb[i >> 4][80 + (i & 15)] = 0;   // K-pad cols 80..95
        qkgb[i >> 4][16 + (i & 15)] = 0;  // K-pad cols 16..31
    }
    __syncthreads();
    // ---- q A-fragments: per-thread rows, loaded once, reused everywhere ----
    u16x8 qa0, qa1;
    {
        const unsigned short* qr = qfp + (size_t)(s0 + wave * 16 + l15) * HD + quad * 8;
        qa0.u = *(const uint4*)qr;
        qa1.u = *(const uint4*)(qr + 32);
    }
    // ---- phase A: wave w computes P rows w*16..w*16+15 (wave-private) ----
#pragma unroll
    for (int tj = 0; tj < 5; tj++) {
        int row = tj * 16 + l15;
        int gs = s0 + row - 8;
        bool valid = (row < 78) && (gs >= 0) && (gs < S_);
        int gsc = gs < 0 ? 0 : (gs > S_ - 1 ? S_ - 1 : gs);
        const unsigned short* kr = kfp + (size_t)gsc * HD + quad * 8;
        u16x8 b0, b1, ones;
        ones.u = make_uint4(0x3F803F80u, 0x3F803F80u, 0x3F803F80u, 0x3F803F80u);
        b0.u = *(const uint4*)kr;
        b1.u = *(const uint4*)(kr + 32);
        if (!valid) { b0 = ones; b1 = ones; }
        f32x4 c = {0.f, 0.f, 0.f, 0.f};
        c = __builtin_amdgcn_mfma_f32_16x16x32_bf16(qa0.s, b0.s, c, 0, 0, 0);
        c = __builtin_amdgcn_mfma_f32_16x16x32_bf16(qa1.s, b1.s, c, 0, 0, 0);
        int col = tj * 16 + l15;
#pragma unroll
        for (int rr = 0; rr < 4; rr++) {
            int tok = wave * 16 + quad * 4 + rr;
            int which = col - tok;
            plb[tok][col] = (which >= 2 && which < 14) ? f2bu(c[rr]) : (unsigned short)0;
        }
    }
    {
        f32x4 c = {0.f, 0.f, 0.f, 0.f};
        short8 bfr0 = *(short8*)&aqfb[l15][quad * 8];
        short8 bfr1 = *(short8*)&aqfb[l15][32 + quad * 8];
        c = __builtin_amdgcn_mfma_f32_16x16x32_bf16(qa0.s, bfr0, c, 0, 0, 0);
        c = __builtin_amdgcn_mfma_f32_16x16x32_bf16(qa1.s, bfr1, c, 0, 0, 0);
#pragma unroll
        for (int rr = 0; rr < 4; rr++) qkgb[wave * 16 + quad * 4 + rr][l15] = f2bu(c[rr]);
    }
    // ---- per-wave norms -> reciprocal combine weights (lanes 0-15) ----
    if (lane < 16) {
        int t = wave * 16 + lane;
        float sl = 0.f;
#pragma unroll
        for (int j = 0; j < 12; j++) sl += bu2f(plb[t][t + 2 + j]);
        float sg = 0.f;
#pragma unroll
        for (int a = 0; a < 12; a++) sg += bu2f(qkgb[t][a]);
        nrm[wave][0][lane] = wl / fmaxf(sl, 1e-6f);
        nrm[wave][1][lane] = wg / fmaxf(sg, 1e-6f);
        nrm[wave][2][lane] = wsb / fmaxf(bu2f(qkgb[t][12]), 1e-6f);
    }
    // ---- phase B: fused MFMA; B-frags for stride/global bands direct ----
#pragma unroll
    for (int j2 = 0; j2 < 4; j2++) {
        int e = j2 * 16 + l15;
        f32x4 cL = {0.f, 0.f, 0.f, 0.f};
        f32x4 cG = {0.f, 0.f, 0.f, 0.f};
        f32x4 cS = {0.f, 0.f, 0.f, 0.f};
#pragma unroll
        for (int kk = 0; kk < 3; kk++) {
            short8 afr = *(short8*)&plb[wave * 16 + l15][kk * 32 + quad * 8];
            short8 bfr = *(short8*)&vtbT[e][kk * 32 + quad * 8];
            cL = __builtin_amdgcn_mfma_f32_16x16x32_bf16(afr, bfr, cL, 0, 0, 0);
        }
        {
            short8 afr = *(short8*)&qkgb[wave * 16 + l15][quad * 8];
            u16x8 bo;
            bo.u = make_uint4(0u, 0u, 0u, 0u);
            const unsigned* ap = (const unsigned*)(aoutTb + (size_t)bh * 768 + e * 12);
            if (quad == 0) {
                bo.u.x = ap[0]; bo.u.y = ap[1]; bo.u.z = ap[2]; bo.u.w = ap[3];
            } else if (quad == 1) {
                bo.u.x = ap[4]; bo.u.y = ap[5];
            }
            cG = __builtin_amdgcn_mfma_f32_16x16x32_bf16(afr, bo.s, cG, 0, 0, 0);
        }
        {
            const unsigned short* kvp = kvsTb + (size_t)bh * 4096 + e * 64 + quad * 8;
            u16x8 bk0, bk1;
            bk0.u = *(const uint4*)kvp;
            bk1.u = *(const uint4*)(kvp + 32);
            cS = __builtin_amdgcn_mfma_f32_16x16x32_bf16(qa0.s, bk0.s, cS, 0, 0, 0);
            cS = __builtin_amdgcn_mfma_f32_16x16x32_bf16(qa1.s, bk1.s, cS, 0, 0, 0);
        }
#pragma unroll
        for (int rr = 0; rr < 4; rr++) {
            int tq = quad * 4 + rr;
            int tok = wave * 16 + tq;
            float res = cL[rr] * nrm[wave][0][tq] + cS[rr] * nrm[wave][2][tq] +
                        cG[rr] * nrm[wave][1][tq];
            attnb[((size_t)(b * S_ + s0 + tok)) * 768 + h * 64 + e] = f2bu(res);
        }
    }
}

// ---------------------------------------------------------------------------
// Kernel 4: out = attn(bf16) @ out_w.T, counted-vmcnt dbuf + XCD swizzle.
// ---------------------------------------------------------------------------
__global__ __launch_bounds__(256) void out_gemm_mfma(const unsigned short* __restrict__ attnb,
                                                     const unsigned short* __restrict__ wb,
                                                     float* __restrict__ out) {
    __shared__ __attribute__((aligned(16))) unsigned short As[2][128 * 32];
    __shared__ __attribute__((aligned(16))) unsigned short Bs[2][128 * 32];
    const int K = 768;
    int orig = blockIdx.x;
    int swz = (orig & 7) * 48 + (orig >> 3);
    int mt = swz / 6, nt = swz - mt * 6;
    int n0 = nt * 128, m0 = mt * 128;
    int tid = threadIdx.x, lane = tid & 63, wave = tid >> 6;
    int wm = (wave & 1) * 64, wn = (wave >> 1) * 64;
    int quad = lane >> 4, l15 = lane & 15;
    f32x4 acc[4][4];
#pragma unroll
    for (int i = 0; i < 4; i++)
#pragma unroll
        for (int j = 0; j < 4; j++) acc[i][j] = 0.f;

    const unsigned short* ga0 = attnb + (size_t)(m0 + (tid >> 2)) * K + (tid & 3) * 8;
    const unsigned short* ga1 = attnb + (size_t)(m0 + 64 + (tid >> 2)) * K + (tid & 3) * 8;
    const unsigned short* gb0 = wb + (size_t)(n0 + (tid >> 2)) * K + (tid & 3) * 8;
    const unsigned short* gb1 = wb + (size_t)(n0 + 64 + (tid >> 2)) * K + (tid & 3) * 8;

    auto stage = [&](int bufi, int kk) {
        gload16(ga0 + kk, &As[bufi][wave * 512]);
        gload16(ga1 + kk, &As[bufi][2048 + wave * 512]);
        gload16(gb0 + kk, &Bs[bufi][wave * 512]);
        gload16(gb1 + kk, &Bs[bufi][2048 + wave * 512]);
    };
    auto compute = [&](int bufi) {
        short8 af[4], bfr[4];
#pragma unroll
        for (int i = 0; i < 4; i++)
            af[i] = *(short8*)&As[bufi][(wm + i * 16 + l15) * 32 + quad * 8];
#pragma unroll
        for (int j = 0; j < 4; j++)
            bfr[j] = *(short8*)&Bs[bufi][(wn + j * 16 + l15) * 32 + quad * 8];
#pragma unroll
        for (int i = 0; i < 4; i++)
#pragma unroll
            for (int j = 0; j < 4; j++)
                acc[i][j] = __builtin_amdgcn_mfma_f32_16x16x32_bf16(af[i], bfr[j], acc[i][j], 0, 0, 0);
    };

    stage(0, 0);
    int buf = 0;
    for (int t = 0; t < 23; t++) {
        stage(buf ^ 1, (t + 1) * 32);
        asm volatile("s_waitcnt vmcnt(4)" ::: "memory");
        __builtin_amdgcn_s_barrier();
        __builtin_amdgcn_sched_barrier(0);
        compute(buf);
        asm volatile("" ::: "memory");
        __builtin_amdgcn_s_barrier();
        buf ^= 1;
    }
    asm volatile("s_waitcnt vmcnt(0)" ::: "memory");
    __builtin_amdgcn_s_barrier();
    __builtin_amdgcn_sched_barrier(0);
    compute(buf);

#pragma unroll
    for (int j = 0; j < 4; j++) {
        int col = n0 + wn + j * 16 + l15;
#pragma unroll
        for (int i = 0; i < 4; i++) {
#pragma unroll
            for (int rr = 0; rr < 4; rr++) {
                int m = m0 + wm + i * 16 + quad * 4 + rr;
                out[(size_t)m * 768 + col] = acc[i][j][rr];
            }
        }
    }
}

extern "C" void kernel_launch(void* const* d_in, const int* in_sizes, int n_in,
                              void* d_out, int out_size, void* d_ws, size_t ws_size,
                              hipStream_t stream) {
    const float* x = (const float*)d_in[0];
    const float* qkvw = (const float*)d_in[1];
    const float* outw = (const float*)d_in[2];
    const float* aq = (const float*)d_in[3];
    const float* wlp = (const float*)d_in[4];
    const float* wsp = (const float*)d_in[5];
    const float* wgp = (const float*)d_in[6];

    float* ws = (float*)d_ws;
    const size_t NBH = (size_t)B_ * H_ * S_ * HD;  // 6,291,456
    // [0, 2*NBH floats): bf16 qfb / kfb / kTb / vTb (NBH ushorts each)
    unsigned short* qfb = (unsigned short*)ws;
    unsigned short* kfb = qfb + NBH;
    unsigned short* kTb = kfb + NBH;
    unsigned short* vTb = kTb + NBH;
    float* attn_region = ws + 2 * NBH;  // NBH floats; multi-use scratch
    unsigned short* xb = (unsigned short*)attn_region;
    unsigned short* wb = (unsigned short*)(attn_region + 3145728);
    float* pkv = attn_region;
    unsigned short* attnb = (unsigned short*)attn_region;
    unsigned short* kvsTb = (unsigned short*)(attn_region + NBH);   // 48*4096
    unsigned short* ksumsb = kvsTb + 48 * 4096;                     // 48*64
    unsigned short* aoutTb = ksumsb + 48 * 64;                      // 48*768
    unsigned short* aqfb_g = aoutTb + 48 * 768;                     // 9216
    float* pks = attn_region + NBH + 122880;                        // 768*128 floats
    unsigned short* outwb = (unsigned short*)(pks + 768 * 128);

    convert_all<<<8484, 256, 0, stream>>>(x, qkvw, outw, aq, xb, wb, outwb, aqfb_g);
    qkv_gemm_mfma<<<1152, 256, 0, stream>>>(xb, wb, qfb, kfb, kTb, vTb);
    band_partial<<<48 * 16, 256, 0, stream>>>(kTb, vTb, pkv, pks);
    band_reduce<<<48 * 4, 256, 0, stream>>>(pkv, pks, aq, kvsTb, ksumsb, aoutTb);
    combine<<<48 * 32, 256, 0, stream>>>(qfb, kfb, vTb, aqfb_g, kvsTb, ksumsb, aoutTb,
                                         wlp, wsp, wgp, attnb);
    out_gemm_mfma<<<384, 256, 0, stream>>>(attnb, outwb, (float*)d_out);
}

// Round 14
// 212.897 us; speedup vs baseline: 1.3269x; 1.0265x over previous
//
#include <hip/hip_runtime.h>
#include <hip/hip_bf16.h>

#define B_ 4
#define S_ 2048
#define D_ 768
#define H_ 12
#define HD 64

typedef __attribute__((ext_vector_type(8))) short short8;
typedef __attribute__((ext_vector_type(4))) float f32x4;

__device__ __forceinline__ float fmapf(float x) { return x > 0.f ? x + 1.f : __expf(x); }

// fp32 -> bf16 round-to-nearest-even (finite inputs only)
__device__ __forceinline__ unsigned short f2bu(float f) {
    unsigned u = __float_as_uint(f);
    u += 0x7FFFu + ((u >> 16) & 1u);
    return (unsigned short)(u >> 16);
}
__device__ __forceinline__ float bu2f(unsigned short v) {
    return __uint_as_float((unsigned)v << 16);
}

// async global->LDS direct copy, 16B per lane. lds ptr must be wave-uniform;
// HW writes lane l to ldsbase + l*16 (m97 pattern: linear LDS dest).
__device__ __forceinline__ void gload16(const void* g, void* l) {
    __builtin_amdgcn_global_load_lds((__attribute__((address_space(1))) void*)(size_t)g,
                                     (__attribute__((address_space(3))) void*)l, 16, 0, 0);
}

union u16x8 {
    uint4 u;
    short8 s;
    unsigned short h[8];
};

// ---------------------------------------------------------------------------
// Kernel 0: fused fp32->bf16 converts for x, qkv_w, out_w + fmap(anchor_q).
// ---------------------------------------------------------------------------
__global__ __launch_bounds__(256) void convert_all(const float* __restrict__ x,
                                                   const float* __restrict__ qkvw,
                                                   const float* __restrict__ outw,
                                                   const float* __restrict__ aq,
                                                   unsigned short* __restrict__ xb,
                                                   unsigned short* __restrict__ wb,
                                                   unsigned short* __restrict__ outwb,
                                                   unsigned short* __restrict__ aqfb_g) {
    int gid = blockIdx.x * 256 + threadIdx.x;
    const float* src;
    unsigned short* dst;
    int i4;
    if (gid < 1572864) {
        src = x; dst = xb; i4 = gid;
    } else if (gid < 1572864 + 442368) {
        src = qkvw; dst = wb; i4 = gid - 1572864;
    } else if (gid < 2162688) {
        src = outw; dst = outwb; i4 = gid - (1572864 + 442368);
    } else {
        int i = gid - 2162688;  // < 9216
        aqfb_g[i] = f2bu(fmapf(aq[i]));
        return;
    }
    float4 v = *(const float4*)&src[i4 * 4];
    ushort4 o;
    o.x = f2bu(v.x); o.y = f2bu(v.y); o.z = f2bu(v.z); o.w = f2bu(v.w);
    *(ushort4*)&dst[i4 * 4] = o;
}

// ---------------------------------------------------------------------------
// Kernel 1: qkv = x @ qkv_w.T via bf16 MFMA. dbuf + XCD swizzle + counted
// vmcnt + LDS-staged coalesced epilogue (unchanged from round 13).
// ---------------------------------------------------------------------------
__global__ __launch_bounds__(256) void qkv_gemm_mfma(const unsigned short* __restrict__ xb,
                                                     const unsigned short* __restrict__ wb,
                                                     unsigned short* __restrict__ qfb,
                                                     unsigned short* __restrict__ kfb,
                                                     unsigned short* __restrict__ kTb,
                                                     unsigned short* __restrict__ vTb) {
    __shared__ __attribute__((aligned(16))) unsigned short shmem[18432];
    const int K = 768;
    int orig = blockIdx.x;
    int swz = (orig & 7) * 144 + (orig >> 3);
    int mt = swz / 18, nt = swz - mt * 18;
    int n0 = nt * 128, m0 = mt * 128;
    int tid = threadIdx.x, lane = tid & 63, wave = tid >> 6;
    int wm = (wave & 1) * 64, wn = (wave >> 1) * 64;
    int quad = lane >> 4, l15 = lane & 15;
    f32x4 acc[4][4];
#pragma unroll
    for (int i = 0; i < 4; i++)
#pragma unroll
        for (int j = 0; j < 4; j++) acc[i][j] = 0.f;

    const unsigned short* ga0 = xb + (size_t)(m0 + (tid >> 2)) * K + (tid & 3) * 8;
    const unsigned short* ga1 = xb + (size_t)(m0 + 64 + (tid >> 2)) * K + (tid & 3) * 8;
    const unsigned short* gb0 = wb + (size_t)(n0 + (tid >> 2)) * K + (tid & 3) * 8;
    const unsigned short* gb1 = wb + (size_t)(n0 + 64 + (tid >> 2)) * K + (tid & 3) * 8;

    auto stage = [&](int bufi, int kk) {
        gload16(ga0 + kk, shmem + bufi * 4096 + wave * 512);
        gload16(ga1 + kk, shmem + bufi * 4096 + 2048 + wave * 512);
        gload16(gb0 + kk, shmem + 8192 + bufi * 4096 + wave * 512);
        gload16(gb1 + kk, shmem + 8192 + bufi * 4096 + 2048 + wave * 512);
    };
    auto compute = [&](int bufi) {
        short8 af[4], bfr[4];
#pragma unroll
        for (int i = 0; i < 4; i++)
            af[i] = *(short8*)&shmem[bufi * 4096 + (wm + i * 16 + l15) * 32 + quad * 8];
#pragma unroll
        for (int j = 0; j < 4; j++)
            bfr[j] = *(short8*)&shmem[8192 + bufi * 4096 + (wn + j * 16 + l15) * 32 + quad * 8];
#pragma unroll
        for (int i = 0; i < 4; i++)
#pragma unroll
            for (int j = 0; j < 4; j++)
                acc[i][j] = __builtin_amdgcn_mfma_f32_16x16x32_bf16(af[i], bfr[j], acc[i][j], 0, 0, 0);
    };

    stage(0, 0);
    int buf = 0;
    for (int t = 0; t < 23; t++) {
        stage(buf ^ 1, (t + 1) * 32);
        asm volatile("s_waitcnt vmcnt(4)" ::: "memory");
        __builtin_amdgcn_s_barrier();
        __builtin_amdgcn_sched_barrier(0);
        compute(buf);
        asm volatile("" ::: "memory");
        __builtin_amdgcn_s_barrier();
        buf ^= 1;
    }
    asm volatile("s_waitcnt vmcnt(0)" ::: "memory");
    __builtin_amdgcn_s_barrier();
    __builtin_amdgcn_sched_barrier(0);
    compute(buf);

    // ---- epilogue ----
    __syncthreads();  // all waves done reading staging buffers
    {
        int colbase = n0 + wn;            // 64-aligned -> t3, h wave-uniform
        int t3 = colbase / 768;
        int r = colbase - t3 * 768;
        int h = r >> 6;
        int mstart = m0 + wm;
        int bb = mstart >> 11, sstart = mstart & 2047;
        unsigned short* ldsw = shmem + wave * 4608;  // per-wave 64x72 tile
        if (t3 <= 1) {
            // normal [tok][col] fill + coalesced store (q, k)
#pragma unroll
            for (int j = 0; j < 4; j++)
#pragma unroll
                for (int i = 0; i < 4; i++)
#pragma unroll
                    for (int rr = 0; rr < 4; rr++) {
                        float val = acc[i][j][rr];
                        ldsw[(i * 16 + quad * 4 + rr) * 72 + j * 16 + l15] = f2bu(fmapf(val));
                    }
            unsigned short* gbp = (t3 == 0 ? qfb : kfb) +
                                  (((size_t)(bb * H_ + h) * S_) + sstart) * (size_t)HD;
#pragma unroll
            for (int c = 0; c < 8; c++) {
                int tok = c * 8 + (lane >> 3);
                uint4 vd = *(uint4*)&ldsw[tok * 72 + (lane & 7) * 8];
                *(uint4*)&gbp[(size_t)tok * 64 + (lane & 7) * 8] = vd;
            }
        }
        if (t3 >= 1) {
            // transposed [d][tok] fill + coalesced store (k -> kTb, v -> vTb).
            // Per-wave LDS ops are in-order, so refill after the reads is safe.
#pragma unroll
            for (int j = 0; j < 4; j++)
#pragma unroll
                for (int i = 0; i < 4; i++)
#pragma unroll
                    for (int rr = 0; rr < 4; rr++) {
                        float val = acc[i][j][rr];
                        unsigned short o = (t3 == 1) ? f2bu(fmapf(val)) : f2bu(val);
                        ldsw[(j * 16 + l15) * 72 + i * 16 + quad * 4 + rr] = o;
                    }
            unsigned short* gt = (t3 == 1 ? kTb : vTb) +
                                 ((size_t)(bb * H_ + h) * 64) * (size_t)S_ + sstart;
#pragma unroll
            for (int c = 0; c < 8; c++) {
                int d = c * 8 + (lane >> 3);
                uint4 vd = *(uint4*)&ldsw[d * 72 + (lane & 7) * 8];
                *(uint4*)&gt[(size_t)d * S_ + (lane & 7) * 8] = vd;
            }
        }
    }
}

// ---------------------------------------------------------------------------
// Kernel 2a: partial kv states via MFMA. Grid = 48 bh * 8 chunks (256 tokens
// each): halves pkv/pks partial traffic vs 16 chunks (band_partial is MFMA-
// cheap; band_reduce's reduction loop halves). Wave w owns d-rows [16w,+16).
// ---------------------------------------------------------------------------
__global__ __launch_bounds__(256) void band_partial(const unsigned short* __restrict__ kTb,
                                                    const unsigned short* __restrict__ vTb,
                                                    float* __restrict__ pkv,
                                                    float* __restrict__ pks) {
    int bh = blockIdx.x >> 3, chunk = blockIdx.x & 7;
    int s0 = chunk * 256;
    int tid = threadIdx.x, lane = tid & 63, wave = tid >> 6;
    int quad = lane >> 4, l15 = lane & 15;
    const unsigned short* kT = kTb + (size_t)bh * 64 * S_;
    const unsigned short* vT = vTb + (size_t)bh * 64 * S_;
    f32x4 cg[4], cs[4], og, os;
#pragma unroll
    for (int j = 0; j < 4; j++) { cg[j] = 0.f; cs[j] = 0.f; }
    og = 0.f; os = 0.f;
    u16x8 ONES;
    ONES.u = make_uint4(0x3F803F80u, 0x3F803F80u, 0x3F803F80u, 0x3F803F80u);
    // stride masks: element i kept iff (r+i)%3==0, r = s%3 of first element
    const uint4 M0 = make_uint4(0x0000FFFFu, 0xFFFF0000u, 0u, 0x0000FFFFu);
    const uint4 M1 = make_uint4(0u, 0x0000FFFFu, 0xFFFF0000u, 0u);
    const uint4 M2 = make_uint4(0xFFFF0000u, 0u, 0x0000FFFFu, 0xFFFF0000u);
#pragma unroll
    for (int st = 0; st < 8; st++) {
        int sb = s0 + st * 32 + quad * 8;
        u16x8 A;
        A.u = *(const uint4*)&kT[(size_t)(wave * 16 + l15) * S_ + sb];
        int rmod = sb % 3;
        uint4 m = (rmod == 0) ? M0 : ((rmod == 1) ? M1 : M2);
        u16x8 Am;
        Am.u.x = A.u.x & m.x; Am.u.y = A.u.y & m.y;
        Am.u.z = A.u.z & m.z; Am.u.w = A.u.w & m.w;
        og = __builtin_amdgcn_mfma_f32_16x16x32_bf16(A.s, ONES.s, og, 0, 0, 0);
        os = __builtin_amdgcn_mfma_f32_16x16x32_bf16(Am.s, ONES.s, os, 0, 0, 0);
#pragma unroll
        for (int j = 0; j < 4; j++) {
            u16x8 Bf;
            Bf.u = *(const uint4*)&vT[(size_t)(j * 16 + l15) * S_ + sb];
            cg[j] = __builtin_amdgcn_mfma_f32_16x16x32_bf16(A.s, Bf.s, cg[j], 0, 0, 0);
            cs[j] = __builtin_amdgcn_mfma_f32_16x16x32_bf16(Am.s, Bf.s, cs[j], 0, 0, 0);
        }
    }
    float* pg = pkv + (size_t)blockIdx.x * 2 * 4096;
#pragma unroll
    for (int j = 0; j < 4; j++)
#pragma unroll
        for (int rr = 0; rr < 4; rr++) {
            int d = wave * 16 + quad * 4 + rr;
            int e = j * 16 + l15;
            pg[d * 64 + e] = cg[j][rr];
            pg[4096 + d * 64 + e] = cs[j][rr];
        }
    if (l15 == 0) {
#pragma unroll
        for (int rr = 0; rr < 4; rr++) {
            int d = wave * 16 + quad * 4 + rr;
            pks[blockIdx.x * 128 + d] = og[rr];
            pks[blockIdx.x * 128 + 64 + d] = os[rr];
        }
    }
}

// ---------------------------------------------------------------------------
// Kernel 2b: reduce partials (8/bh) + anchor outputs. Grid = 48*4.
// ---------------------------------------------------------------------------
__global__ __launch_bounds__(256) void band_reduce(const float* __restrict__ pkv,
                                                   const float* __restrict__ pks,
                                                   const float* __restrict__ aq,
                                                   unsigned short* __restrict__ kvsTb,
                                                   unsigned short* __restrict__ ksumsb,
                                                   unsigned short* __restrict__ aoutTb) {
    int bh = blockIdx.x >> 2, eb = blockIdx.x & 3, e0 = eb * 16;
    int h = bh % H_;
    __shared__ float kvgL[64][17];
    __shared__ float ksgL[64];
    __shared__ float anorm[12];
    int tid = threadIdx.x;
    for (int idx = tid; idx < 1024; idx += 256) {
        int d = idx >> 4, j = idx & 15;
        float sg = 0.f, ss = 0.f;
        const float* p = pkv + (size_t)(bh * 8) * 2 * 4096 + d * 64 + e0 + j;
#pragma unroll 4
        for (int c = 0; c < 8; c++) {
            sg += p[0];
            ss += p[4096];
            p += 2 * 4096;
        }
        kvgL[d][j] = sg;
        kvsTb[(size_t)bh * 4096 + (e0 + j) * 64 + d] = f2bu(ss);
    }
    if (tid < 64) {
        float sg = 0.f, ss = 0.f;
#pragma unroll 4
        for (int c = 0; c < 8; c++) {
            sg += pks[(bh * 8 + c) * 128 + tid];
            ss += pks[(bh * 8 + c) * 128 + 64 + tid];
        }
        ksgL[tid] = sg;
        if (eb == 0) ksumsb[bh * 64 + tid] = f2bu(ss);
    }
    __syncthreads();
    if (tid < 12) {
        float nrm = 0.f;
        for (int dd = 0; dd < 64; dd++)
            nrm += fmapf(aq[h * 768 + tid * 64 + dd]) * ksgL[dd];
        anorm[tid] = fmaxf(nrm, 1e-6f);
    }
    __syncthreads();
    if (tid < 192) {
        int a = tid >> 4, j = tid & 15;
        float acc = 0.f;
        for (int dd = 0; dd < 64; dd++)
            acc += fmapf(aq[h * 768 + a * 64 + dd]) * kvgL[dd][j];
        aoutTb[(size_t)bh * 768 + (e0 + j) * 12 + a] = f2bu(acc / anorm[a]);
    }
}

// ---------------------------------------------------------------------------
// Kernel 3: combine — register-direct MFMA fragments. Phase B now computes
// all 4 e-tiles into registers, then writes bf16 results into the wave-
// private plb rows and stores attnb with full-line coalesced dwordx4 bursts
// (r10 lesson applied to combine: kills 2B-scattered RMW write
// amplification). Bit-identical values.
// ---------------------------------------------------------------------------
__global__ __launch_bounds__(256) void combine(const unsigned short* __restrict__ qfb,
                                               const unsigned short* __restrict__ kfb,
                                               const unsigned short* __restrict__ vTb,
                                               const unsigned short* __restrict__ aqfb_g,
                                               const unsigned short* __restrict__ kvsTb,
                                               const unsigned short* __restrict__ ksumsb,
                                               const unsigned short* __restrict__ aoutTb,
                                               const float* __restrict__ wlp,
                                               const float* __restrict__ wsp,
                                               const float* __restrict__ wgp,
                                               unsigned short* __restrict__ attnb) {
    __shared__ __attribute__((aligned(16))) unsigned short aqfb[16][72];   // anchors + ksum
    __shared__ __attribute__((aligned(16))) unsigned short vtbT[64][104];  // [e][band k], k<96
    __shared__ __attribute__((aligned(16))) unsigned short plb[64][104];   // masked P / out stage
    __shared__ __attribute__((aligned(16))) unsigned short qkgb[64][40];   // [token][anchor k]
    __shared__ float nrm[4][3][16];
    int bh = blockIdx.x >> 5, stile = blockIdx.x & 31;
    int b = bh / H_, h = bh % H_;
    int s0 = stile * 64;
    int tid = threadIdx.x, lane = tid & 63, wave = tid >> 6;
    int quad = lane >> 4, l15 = lane & 15;
    const unsigned short* qfp = qfb + (size_t)bh * S_ * HD;
    const unsigned short* kfp = kfb + (size_t)bh * S_ * HD;
    const unsigned short* vTp = vTb + (size_t)bh * 64 * S_;
    float a0 = wlp[0], a1 = wsp[0], a2 = wgp[0];
    float mx = fmaxf(a0, fmaxf(a1, a2));
    float ew0 = __expf(a0 - mx), ew1 = __expf(a1 - mx), ew2 = __expf(a2 - mx);
    float inv = 1.f / (ew0 + ew1 + ew2);
    float wl = ew0 * inv, wsb = ew1 * inv, wg = ew2 * inv;
    // ---- stage: vtbT via vector row copies from vTb; aqfb; K-pads ----
    for (int u = tid; u < 64 * 12; u += 256) {
        int e = u & 63, c = u >> 6;  // c in [0,12): 8-col chunk
        int k0 = c * 8;
        int gs0 = s0 - 8 + k0;
        const unsigned short* src = vTp + (size_t)e * S_ + gs0;
        if (gs0 >= 0 && gs0 + 8 <= S_) {
            *(uint4*)&vtbT[e][k0] = *(const uint4*)src;
        } else {
#pragma unroll
            for (int i = 0; i < 8; i++) {
                int gs = gs0 + i;
                vtbT[e][k0 + i] = (gs >= 0 && gs < S_) ? src[i] : (unsigned short)0;
            }
        }
    }
    if (tid < 192) {
        int a = tid >> 4, c = (tid & 15) * 4;
        *(ushort4*)&aqfb[a][c] = *(const ushort4*)&aqfb_g[h * 768 + a * 64 + c];
    }
    if (tid < 64) aqfb[12][tid] = ksumsb[bh * 64 + tid];
    if (tid < 192) aqfb[13 + (tid >> 6)][tid & 63] = 0;
    for (int i = tid; i < 1024; i += 256) {
        plb[i >> 4][80 + (i & 15)] = 0;   // K-pad cols 80..95
        qkgb[i >> 4][16 + (i & 15)] = 0;  // K-pad cols 16..31
    }
    __syncthreads();
    // ---- q A-fragments: per-thread rows, loaded once, reused everywhere ----
    u16x8 qa0, qa1;
    {
        const unsigned short* qr = qfp + (size_t)(s0 + wave * 16 + l15) * HD + quad * 8;
        qa0.u = *(const uint4*)qr;
        qa1.u = *(const uint4*)(qr + 32);
    }
    // ---- phase A: wave w computes P rows w*16..w*16+15 (wave-private) ----
#pragma unroll
    for (int tj = 0; tj < 5; tj++) {
        int row = tj * 16 + l15;
        int gs = s0 + row - 8;
        bool valid = (row < 78) && (gs >= 0) && (gs < S_);
        int gsc = gs < 0 ? 0 : (gs > S_ - 1 ? S_ - 1 : gs);
        const unsigned short* kr = kfp + (size_t)gsc * HD + quad * 8;
        u16x8 b0, b1, ones;
        ones.u = make_uint4(0x3F803F80u, 0x3F803F80u, 0x3F803F80u, 0x3F803F80u);
        b0.u = *(const uint4*)kr;
        b1.u = *(const uint4*)(kr + 32);
        if (!valid) { b0 = ones; b1 = ones; }
        f32x4 c = {0.f, 0.f, 0.f, 0.f};
        c = __builtin_amdgcn_mfma_f32_16x16x32_bf16(qa0.s, b0.s, c, 0, 0, 0);
        c = __builtin_amdgcn_mfma_f32_16x16x32_bf16(qa1.s, b1.s, c, 0, 0, 0);
        int col = tj * 16 + l15;
#pragma unroll
        for (int rr = 0; rr < 4; rr++) {
            int tok = wave * 16 + quad * 4 + rr;
            int which = col - tok;
            plb[tok][col] = (which >= 2 && which < 14) ? f2bu(c[rr]) : (unsigned short)0;
        }
    }
    {
        f32x4 c = {0.f, 0.f, 0.f, 0.f};
        short8 bfr0 = *(short8*)&aqfb[l15][quad * 8];
        short8 bfr1 = *(short8*)&aqfb[l15][32 + quad * 8];
        c = __builtin_amdgcn_mfma_f32_16x16x32_bf16(qa0.s, bfr0, c, 0, 0, 0);
        c = __builtin_amdgcn_mfma_f32_16x16x32_bf16(qa1.s, bfr1, c, 0, 0, 0);
#pragma unroll
        for (int rr = 0; rr < 4; rr++) qkgb[wave * 16 + quad * 4 + rr][l15] = f2bu(c[rr]);
    }
    // ---- per-wave norms -> reciprocal combine weights (lanes 0-15) ----
    if (lane < 16) {
        int t = wave * 16 + lane;
        float sl = 0.f;
#pragma unroll
        for (int j = 0; j < 12; j++) sl += bu2f(plb[t][t + 2 + j]);
        float sg = 0.f;
#pragma unroll
        for (int a = 0; a < 12; a++) sg += bu2f(qkgb[t][a]);
        nrm[wave][0][lane] = wl / fmaxf(sl, 1e-6f);
        nrm[wave][1][lane] = wg / fmaxf(sg, 1e-6f);
        nrm[wave][2][lane] = wsb / fmaxf(bu2f(qkgb[t][12]), 1e-6f);
    }
    // ---- phase B: compute ALL e-tiles into registers first ----
    f32x4 resv[4];
#pragma unroll
    for (int j2 = 0; j2 < 4; j2++) {
        int e = j2 * 16 + l15;
        f32x4 cL = {0.f, 0.f, 0.f, 0.f};
        f32x4 cG = {0.f, 0.f, 0.f, 0.f};
        f32x4 cS = {0.f, 0.f, 0.f, 0.f};
#pragma unroll
        for (int kk = 0; kk < 3; kk++) {
            short8 afr = *(short8*)&plb[wave * 16 + l15][kk * 32 + quad * 8];
            short8 bfr = *(short8*)&vtbT[e][kk * 32 + quad * 8];
            cL = __builtin_amdgcn_mfma_f32_16x16x32_bf16(afr, bfr, cL, 0, 0, 0);
        }
        {
            short8 afr = *(short8*)&qkgb[wave * 16 + l15][quad * 8];
            u16x8 bo;
            bo.u = make_uint4(0u, 0u, 0u, 0u);
            const unsigned* ap = (const unsigned*)(aoutTb + (size_t)bh * 768 + e * 12);
            if (quad == 0) {
                bo.u.x = ap[0]; bo.u.y = ap[1]; bo.u.z = ap[2]; bo.u.w = ap[3];
            } else if (quad == 1) {
                bo.u.x = ap[4]; bo.u.y = ap[5];
            }
            cG = __builtin_amdgcn_mfma_f32_16x16x32_bf16(afr, bo.s, cG, 0, 0, 0);
        }
        {
            const unsigned short* kvp = kvsTb + (size_t)bh * 4096 + e * 64 + quad * 8;
            u16x8 bk0, bk1;
            bk0.u = *(const uint4*)kvp;
            bk1.u = *(const uint4*)(kvp + 32);
            cS = __builtin_amdgcn_mfma_f32_16x16x32_bf16(qa0.s, bk0.s, cS, 0, 0, 0);
            cS = __builtin_amdgcn_mfma_f32_16x16x32_bf16(qa1.s, bk1.s, cS, 0, 0, 0);
        }
#pragma unroll
        for (int rr = 0; rr < 4; rr++) {
            int tq = quad * 4 + rr;
            resv[j2][rr] = cL[rr] * nrm[wave][0][tq] + cS[rr] * nrm[wave][2][tq] +
                           cG[rr] * nrm[wave][1][tq];
        }
    }
    // ---- write results into wave-private plb rows (in-order LDS: safe
    // after all phase-B reads), then fully-coalesced attnb store ----
#pragma unroll
    for (int j2 = 0; j2 < 4; j2++)
#pragma unroll
        for (int rr = 0; rr < 4; rr++)
            plb[wave * 16 + quad * 4 + rr][j2 * 16 + l15] = f2bu(resv[j2][rr]);
    {
        unsigned short* gbp = attnb + ((size_t)(b * S_ + s0 + wave * 16)) * 768 + h * 64;
#pragma unroll
        for (int c = 0; c < 2; c++) {
            int tok = c * 8 + (lane >> 3);
            uint4 vd = *(uint4*)&plb[wave * 16 + tok][(lane & 7) * 8];
            *(uint4*)&gbp[(size_t)tok * 768 + (lane & 7) * 8] = vd;
        }
    }
}

// ---------------------------------------------------------------------------
// Kernel 4: out = attn(bf16) @ out_w.T, counted-vmcnt dbuf + XCD swizzle.
// ---------------------------------------------------------------------------
__global__ __launch_bounds__(256) void out_gemm_mfma(const unsigned short* __restrict__ attnb,
                                                     const unsigned short* __restrict__ wb,
                                                     float* __restrict__ out) {
    __shared__ __attribute__((aligned(16))) unsigned short As[2][128 * 32];
    __shared__ __attribute__((aligned(16))) unsigned short Bs[2][128 * 32];
    const int K = 768;
    int orig = blockIdx.x;
    int swz = (orig & 7) * 48 + (orig >> 3);
    int mt = swz / 6, nt = swz - mt * 6;
    int n0 = nt * 128, m0 = mt * 128;
    int tid = threadIdx.x, lane = tid & 63, wave = tid >> 6;
    int wm = (wave & 1) * 64, wn = (wave >> 1) * 64;
    int quad = lane >> 4, l15 = lane & 15;
    f32x4 acc[4][4];
#pragma unroll
    for (int i = 0; i < 4; i++)
#pragma unroll
        for (int j = 0; j < 4; j++) acc[i][j] = 0.f;

    const unsigned short* ga0 = attnb + (size_t)(m0 + (tid >> 2)) * K + (tid & 3) * 8;
    const unsigned short* ga1 = attnb + (size_t)(m0 + 64 + (tid >> 2)) * K + (tid & 3) * 8;
    const unsigned short* gb0 = wb + (size_t)(n0 + (tid >> 2)) * K + (tid & 3) * 8;
    const unsigned short* gb1 = wb + (size_t)(n0 + 64 + (tid >> 2)) * K + (tid & 3) * 8;

    auto stage = [&](int bufi, int kk) {
        gload16(ga0 + kk, &As[bufi][wave * 512]);
        gload16(ga1 + kk, &As[bufi][2048 + wave * 512]);
        gload16(gb0 + kk, &Bs[bufi][wave * 512]);
        gload16(gb1 + kk, &Bs[bufi][2048 + wave * 512]);
    };
    auto compute = [&](int bufi) {
        short8 af[4], bfr[4];
#pragma unroll
        for (int i = 0; i < 4; i++)
            af[i] = *(short8*)&As[bufi][(wm + i * 16 + l15) * 32 + quad * 8];
#pragma unroll
        for (int j = 0; j < 4; j++)
            bfr[j] = *(short8*)&Bs[bufi][(wn + j * 16 + l15) * 32 + quad * 8];
#pragma unroll
        for (int i = 0; i < 4; i++)
#pragma unroll
            for (int j = 0; j < 4; j++)
                acc[i][j] = __builtin_amdgcn_mfma_f32_16x16x32_bf16(af[i], bfr[j], acc[i][j], 0, 0, 0);
    };

    stage(0, 0);
    int buf = 0;
    for (int t = 0; t < 23; t++) {
        stage(buf ^ 1, (t + 1) * 32);
        asm volatile("s_waitcnt vmcnt(4)" ::: "memory");
        __builtin_amdgcn_s_barrier();
        __builtin_amdgcn_sched_barrier(0);
        compute(buf);
        asm volatile("" ::: "memory");
        __builtin_amdgcn_s_barrier();
        buf ^= 1;
    }
    asm volatile("s_waitcnt vmcnt(0)" ::: "memory");
    __builtin_amdgcn_s_barrier();
    __builtin_amdgcn_sched_barrier(0);
    compute(buf);

#pragma unroll
    for (int j = 0; j < 4; j++) {
        int col = n0 + wn + j * 16 + l15;
#pragma unroll
        for (int i = 0; i < 4; i++) {
#pragma unroll
            for (int rr = 0; rr < 4; rr++) {
                int m = m0 + wm + i * 16 + quad * 4 + rr;
                out[(size_t)m * 768 + col] = acc[i][j][rr];
            }
        }
    }
}

extern "C" void kernel_launch(void* const* d_in, const int* in_sizes, int n_in,
                              void* d_out, int out_size, void* d_ws, size_t ws_size,
                              hipStream_t stream) {
    const float* x = (const float*)d_in[0];
    const float* qkvw = (const float*)d_in[1];
    const float* outw = (const float*)d_in[2];
    const float* aq = (const float*)d_in[3];
    const float* wlp = (const float*)d_in[4];
    const float* wsp = (const float*)d_in[5];
    const float* wgp = (const float*)d_in[6];

    float* ws = (float*)d_ws;
    const size_t NBH = (size_t)B_ * H_ * S_ * HD;  // 6,291,456
    // [0, 2*NBH floats): bf16 qfb / kfb / kTb / vTb (NBH ushorts each)
    unsigned short* qfb = (unsigned short*)ws;
    unsigned short* kfb = qfb + NBH;
    unsigned short* kTb = kfb + NBH;
    unsigned short* vTb = kTb + NBH;
    float* attn_region = ws + 2 * NBH;  // NBH floats; multi-use scratch
    unsigned short* xb = (unsigned short*)attn_region;
    unsigned short* wb = (unsigned short*)(attn_region + 3145728);
    float* pkv = attn_region;
    unsigned short* attnb = (unsigned short*)attn_region;
    unsigned short* kvsTb = (unsigned short*)(attn_region + NBH);   // 48*4096
    unsigned short* ksumsb = kvsTb + 48 * 4096;                     // 48*64
    unsigned short* aoutTb = ksumsb + 48 * 64;                      // 48*768
    unsigned short* aqfb_g = aoutTb + 48 * 768;                     // 9216
    float* pks = attn_region + NBH + 122880;                        // 384*128 floats
    unsigned short* outwb = (unsigned short*)(pks + 384 * 128);

    convert_all<<<8484, 256, 0, stream>>>(x, qkvw, outw, aq, xb, wb, outwb, aqfb_g);
    qkv_gemm_mfma<<<1152, 256, 0, stream>>>(xb, wb, qfb, kfb, kTb, vTb);
    band_partial<<<48 * 8, 256, 0, stream>>>(kTb, vTb, pkv, pks);
    band_reduce<<<48 * 4, 256, 0, stream>>>(pkv, pks, aq, kvsTb, ksumsb, aoutTb);
    combine<<<48 * 32, 256, 0, stream>>>(qfb, kfb, vTb, aqfb_g, kvsTb, ksumsb, aoutTb,
                                         wlp, wsp, wgp, attnb);
    out_gemm_mfma<<<384, 256, 0, stream>>>(attnb, outwb, (float*)d_out);
}